// Round 12
// baseline (491.910 us; speedup 1.0000x reference)
//
#include <hip/hip_runtime.h>

typedef unsigned short u16;
typedef __attribute__((ext_vector_type(8))) _Float16 f16x8;
typedef __attribute__((ext_vector_type(4))) float f32x4;

// GW=16 gw tokens; per-batch seq t = 2048+16 = 2064; total rows 2*2064 = 4128.
#define TPB 2064
#define NROW 4128

__device__ __forceinline__ u16 f2h(float f) {
    _Float16 h = (_Float16)f;
    return __builtin_bit_cast(u16, h);
}
__device__ __forceinline__ float h2f(u16 u) {
    return (float)__builtin_bit_cast(_Float16, u);
}
__device__ __forceinline__ float wave_sum(float v) {
    #pragma unroll
    for (int m = 32; m; m >>= 1) v += __shfl_xor(v, m, 64);
    return v;
}
__device__ __forceinline__ void gl_lds16(const u16* g, u16* l) {
    __builtin_amdgcn_global_load_lds((const __attribute__((address_space(1))) void*)g,
                                     (__attribute__((address_space(3))) void*)l, 16, 0, 0);
}

// ---------- weight transpose-convert: f32 [K][N] -> fp16 [N][K] ----------
__global__ __launch_bounds__(256) void wconv_t_kernel(const float* __restrict__ src,
                                                      u16* __restrict__ dst, int K, int N) {
    __shared__ float tile[32][33];
    const int k0 = blockIdx.y * 32, n0 = blockIdx.x * 32;
    const int tx = threadIdx.x & 31, ty0 = threadIdx.x >> 5;
    #pragma unroll
    for (int r = 0; r < 4; r++) {
        int ky = ty0 + r * 8;
        tile[ky][tx] = src[(size_t)(k0 + ky) * N + n0 + tx];
    }
    __syncthreads();
    #pragma unroll
    for (int r = 0; r < 4; r++) {
        int ny = ty0 + r * 8;
        dst[(size_t)(n0 + ny) * K + k0 + tx] = f2h(tile[tx][ny]);
    }
}

// ---------- RMSNorm(x) + prepend RAW gw tokens (16) -> h fp16 [4128][1024] ----------
__global__ __launch_bounds__(256) void rms_in_kernel(const float* __restrict__ x,
                                                     const float* __restrict__ w,
                                                     const float* __restrict__ gwp,
                                                     u16* __restrict__ h) {
    const int r = blockIdx.x;                 // 0..4127
    const int b = r / TPB, pos = r - b * TPB;
    const int tid = threadIdx.x;
    u16* hr = h + (size_t)r * 1024;
    if (pos < 16) {                           // raw gw tokens (not normalized)
        const float* s = gwp + (size_t)pos * 1024;
        for (int c = tid; c < 1024; c += 256) hr[c] = f2h(s[c]);
        return;
    }
    const float* xr = x + ((size_t)b * 2048 + (pos - 16)) * 1024;
    float v[4]; float ss = 0.f;
    #pragma unroll
    for (int i = 0; i < 4; i++) { v[i] = xr[tid + 256 * i]; ss += v[i] * v[i]; }
    ss = wave_sum(ss);
    __shared__ float red[4];
    if ((tid & 63) == 0) red[tid >> 6] = ss;
    __syncthreads();
    float tot = red[0] + red[1] + red[2] + red[3];
    float rn = rsqrtf(tot * (1.f / 1024.f) + 1e-6f);
    #pragma unroll
    for (int i = 0; i < 4; i++) hr[tid + 256 * i] = f2h(v[i] * rn * w[tid + 256 * i]);
}

// ---------- RMSNorm(y f32 [4096][1024]) -> z fp16 ----------
__global__ __launch_bounds__(256) void rms_row_kernel(const float* __restrict__ in,
                                                      const float* __restrict__ w,
                                                      u16* __restrict__ out) {
    const int r = blockIdx.x;
    const int tid = threadIdx.x;
    const float* xr = in + (size_t)r * 1024;
    float v[4]; float ss = 0.f;
    #pragma unroll
    for (int i = 0; i < 4; i++) { v[i] = xr[tid + 256 * i]; ss += v[i] * v[i]; }
    ss = wave_sum(ss);
    __shared__ float red[4];
    if ((tid & 63) == 0) red[tid >> 6] = ss;
    __syncthreads();
    float tot = red[0] + red[1] + red[2] + red[3];
    float rn = rsqrtf(tot * (1.f / 1024.f) + 1e-6f);
    u16* orow = out + (size_t)r * 1024;
    #pragma unroll
    for (int i = 0; i < 4; i++) orow[tid + 256 * i] = f2h(v[i] * rn * w[tid + 256 * i]);
}

// ---------- GEMM C[M][N] = A[M][K] * Bt[N][K]^T  (fp16 in, m97 structure) ----------
__device__ __forceinline__ void stage_tile(const u16* __restrict__ A, const u16* __restrict__ B,
                                           u16* As, u16* Bs, int m0, int n0, int k0,
                                           int M, int K, int tid) {
    const int wb = tid & ~63;
    #pragma unroll
    for (int t = 0; t < 2; t++) {
        int seg = t * 256 + tid;
        int row = seg >> 2, kc = seg & 3;
        int ar = m0 + row; if (ar > M - 1) ar = M - 1;
        gl_lds16(A + (size_t)ar * K + k0 + kc * 8, As + (size_t)(t * 256 + wb) * 8);
        gl_lds16(B + (size_t)(n0 + row) * K + k0 + kc * 8, Bs + (size_t)(t * 256 + wb) * 8);
    }
}

template <int EPI>
__global__ __launch_bounds__(256, 2) void gemm_bt(const u16* __restrict__ A,
                                                  const u16* __restrict__ B,
                                                  void* Cout,
                                                  const void* aux,
                                                  int M, int N, int K) {
    __shared__ __align__(16) u16 As[2][4096];
    __shared__ __align__(16) u16 Bs[2][4096];
    const int tid = threadIdx.x;
    const int m0 = blockIdx.y * 128, n0 = blockIdx.x * 128;
    const int w = tid >> 6, l = tid & 63;
    const int wr = w >> 1, wc = w & 1, lr = l & 15, lg = l >> 4;
    f32x4 acc[4][4] = {};
    const int NT = K >> 5;
    stage_tile(A, B, As[0], Bs[0], m0, n0, 0, M, K, tid);
    for (int t = 0; t < NT; t++) {
        const int p = t & 1;
        __syncthreads();                       // drains vmcnt(0): staged tile ready
        if (t + 1 < NT) stage_tile(A, B, As[p ^ 1], Bs[p ^ 1], m0, n0, (t + 1) * 32, M, K, tid);
        f16x8 af[4], bf[4];
        #pragma unroll
        for (int i = 0; i < 4; i++) {
            af[i] = *(const f16x8*)&As[p][(wr * 64 + i * 16 + lr) * 32 + lg * 8];
            bf[i] = *(const f16x8*)&Bs[p][(wc * 64 + i * 16 + lr) * 32 + lg * 8];
        }
        #pragma unroll
        for (int i = 0; i < 4; i++)
            #pragma unroll
            for (int j = 0; j < 4; j++)
                acc[i][j] = __builtin_amdgcn_mfma_f32_16x16x32_f16(af[i], bf[j], acc[i][j], 0, 0, 0);
    }
    #pragma unroll
    for (int i = 0; i < 4; i++) {
        const int rowb = m0 + wr * 64 + i * 16 + lg * 4;
        #pragma unroll
        for (int j = 0; j < 4; j++) {
            const int col = n0 + wc * 64 + j * 16 + lr;
            #pragma unroll
            for (int e = 0; e < 4; e++) {
                const int r2 = rowb + e;
                if (r2 < M) {
                    const size_t idx = (size_t)r2 * N + col;
                    const float v = acc[i][j][e];
                    if constexpr (EPI == 0) {
                        ((u16*)Cout)[idx] = f2h(v);
                    } else if constexpr (EPI == 1) {
                        ((float*)Cout)[idx] = v + ((const float*)aux)[idx];
                    } else {
                        float t0 = h2f(((const u16*)aux)[idx]);
                        float s = t0 / (1.f + __expf(-t0));
                        ((u16*)Cout)[idx] = f2h(s * v);
                    }
                }
            }
        }
    }
}

// ---------- flash attention (swapped QK^T, GQA, fused head-RMSNorm), GW=16 ----------
// qkv: fp16 [b*2064][1536]; cols: q h*64 | 1024+g*64 (K) | 1280+g*64 (V)
// out: ctxn fp16 [b*2048][1024] (gw rows dropped). Causal: kv <= qpos (gw always visible).
__global__ __launch_bounds__(256) void attn_kernel(const u16* __restrict__ qkv,
                                                   u16* __restrict__ ctxn,
                                                   const float* __restrict__ hnw) {
    const int qt = blockIdx.x, h = blockIdx.y, b = blockIdx.z;
    const int wv = threadIdx.x >> 6, l = threadIdx.x & 63;
    const int lr = l & 15, lg = l >> 4;
    const int g = h >> 2;
    const int orow0 = qt * 64 + wv * 16;
    const int qpos0 = 16 + orow0;
    const int qpos = qpos0 + lr;           // this lane's q row (S^T col layout)
    const int RS = 1536;
    const int LASTROW = TPB - 1;           // 2063

    const u16* qbase = qkv + (size_t)(b * TPB + qpos) * RS + h * 64;
    const f16x8 qf0 = *(const f16x8*)(qbase + lg * 8);
    const f16x8 qf1 = *(const f16x8*)(qbase + 32 + lg * 8);

    float m = -INFINITY, lsum = 0.f;
    f32x4 oc[4] = {};

    const int sig = 8 * (lr >> 2) + (lr & 3);   // sigma0 row permutation
    const int NT = ((qpos0 + 15) >> 5) + 1;
    for (int kt = 0; kt < NT; kt++) {
        const int kb = kt * 32;
        int kv0 = kb + sig;     int kv0c = kv0 > LASTROW ? LASTROW : kv0;
        int kv1 = kv0 + 4;      int kv1c = kv1 > LASTROW ? LASTROW : kv1;
        const u16* kr0 = qkv + (size_t)(b * TPB + kv0c) * RS + 1024 + g * 64;
        const u16* kr1 = qkv + (size_t)(b * TPB + kv1c) * RS + 1024 + g * 64;
        const f16x8 a0  = *(const f16x8*)(kr0 + lg * 8);
        const f16x8 a0b = *(const f16x8*)(kr0 + 32 + lg * 8);
        const f16x8 a1  = *(const f16x8*)(kr1 + lg * 8);
        const f16x8 a1b = *(const f16x8*)(kr1 + 32 + lg * 8);
        f32x4 st0 = {}, st1 = {};
        st0 = __builtin_amdgcn_mfma_f32_16x16x32_f16(a0,  qf0, st0, 0, 0, 0);
        st0 = __builtin_amdgcn_mfma_f32_16x16x32_f16(a0b, qf1, st0, 0, 0, 0);
        st1 = __builtin_amdgcn_mfma_f32_16x16x32_f16(a1,  qf0, st1, 0, 0, 0);
        st1 = __builtin_amdgcn_mfma_f32_16x16x32_f16(a1b, qf1, st1, 0, 0, 0);
        // lane holds S[q=qpos][kv=kb+8*lg+j] (st0) and kv+4 (st1)
        float sv[8]; float bm = -INFINITY;
        #pragma unroll
        for (int j = 0; j < 4; j++) {
            const int kva = kb + 8 * lg + j;
            float s0 = st0[j] * 0.125f; if (kva > qpos) s0 = -INFINITY;
            float s1 = st1[j] * 0.125f; if (kva + 4 > qpos) s1 = -INFINITY;
            sv[j] = s0; sv[4 + j] = s1;
            bm = fmaxf(bm, fmaxf(s0, s1));
        }
        bm = fmaxf(bm, __shfl_xor(bm, 16, 64));
        bm = fmaxf(bm, __shfl_xor(bm, 32, 64));
        const float nm = fmaxf(m, bm);
        const float sc = __expf(m - nm);
        m = nm;
        float ps = 0.f;
        f16x8 pa;
        #pragma unroll
        for (int j = 0; j < 8; j++) {
            float p = __expf(sv[j] - m);       // masked -> 0
            ps += p;
            pa[j] = (_Float16)p;
        }
        ps += __shfl_xor(ps, 16, 64); ps += __shfl_xor(ps, 32, 64);
        lsum = lsum * sc + ps;
        float scj[4];
        #pragma unroll
        for (int j = 0; j < 4; j++) scj[j] = __shfl(sc, 4 * lg + j, 64);
        #pragma unroll
        for (int dt = 0; dt < 4; dt++)
            #pragma unroll
            for (int j = 0; j < 4; j++) oc[dt][j] *= scj[j];
        // V fragments (scalar gathers, L2-resident) + PV
        f16x8 vf[4];
        #pragma unroll
        for (int j = 0; j < 8; j++) {
            int kv = kb + 8 * lg + j; if (kv > LASTROW) kv = LASTROW;
            const _Float16* vr = (const _Float16*)(qkv + (size_t)(b * TPB + kv) * RS + 1280 + g * 64 + lr);
            #pragma unroll
            for (int dt = 0; dt < 4; dt++) vf[dt][j] = vr[dt * 16];
        }
        #pragma unroll
        for (int dt = 0; dt < 4; dt++)
            oc[dt] = __builtin_amdgcn_mfma_f32_16x16x32_f16(pa, vf[dt], oc[dt], 0, 0, 0);
    }
    // epilogue: /l, head RMSNorm over dv=64, * head_norm_w, store fp16
    float lj[4];
    #pragma unroll
    for (int j = 0; j < 4; j++) lj[j] = __shfl(lsum, 4 * lg + j, 64);
    float o[4][4]; float ssq[4] = {0, 0, 0, 0};
    #pragma unroll
    for (int dt = 0; dt < 4; dt++)
        #pragma unroll
        for (int j = 0; j < 4; j++) {
            float v = oc[dt][j] / lj[j];
            o[dt][j] = v; ssq[j] += v * v;
        }
    float rj[4];
    #pragma unroll
    for (int j = 0; j < 4; j++) {
        float s = ssq[j];
        s += __shfl_xor(s, 1, 64); s += __shfl_xor(s, 2, 64);
        s += __shfl_xor(s, 4, 64); s += __shfl_xor(s, 8, 64);
        rj[j] = rsqrtf(s * (1.f / 64.f) + 1e-6f);
    }
    #pragma unroll
    for (int dt = 0; dt < 4; dt++) {
        const float hw = hnw[h * 64 + dt * 16 + lr];
        #pragma unroll
        for (int j = 0; j < 4; j++) {
            const int orow = orow0 + 4 * lg + j;
            ctxn[(size_t)(b * 2048 + orow) * 1024 + h * 64 + dt * 16 + lr] =
                f2h(o[dt][j] * rj[j] * hw);
        }
    }
}

extern "C" void kernel_launch(void* const* d_in, const int* in_sizes, int n_in,
                              void* d_out, int out_size, void* d_ws, size_t ws_size,
                              hipStream_t stream) {
    const float* x   = (const float*)d_in[0];
    const float* wn  = (const float*)d_in[1];
    const float* gw  = (const float*)d_in[2];
    const float* Wq  = (const float*)d_in[3];
    const float* Wk  = (const float*)d_in[4];
    const float* Wv  = (const float*)d_in[5];
    const float* Wo  = (const float*)d_in[6];
    const float* hnw = (const float*)d_in[7];
    const float* wf  = (const float*)d_in[8];
    const float* W1  = (const float*)d_in[9];
    const float* W3  = (const float*)d_in[10];
    const float* W2  = (const float*)d_in[11];

    char* ws = (char*)d_ws;
    u16*  wqkv = (u16*)(ws + 0);           // [1536][1024] fp16
    u16*  wo_t = (u16*)(ws + 3145728);     // [1024][1024]
    u16*  w1t  = (u16*)(ws + 5242880);     // [4096][1024]
    u16*  w3t  = (u16*)(ws + 13631488);    // [4096][1024]
    u16*  w2t  = (u16*)(ws + 22020096);    // [1024][4096]
    u16*  hbuf = (u16*)(ws + 30408704);    // [4128][1024] fp16 (8,454,144 B)
    u16*  qkvb = (u16*)(ws + 38862848);    // [4128][1536] fp16 (12,681,216 B)
    u16*  ctxn = hbuf;                     // [4096][1024] overlays hbuf (dead after QKV)
    float* yb  = (float*)(ws + 51544064);  // [4096][1024] f32 (16,777,216 B)
    u16*  zb   = (u16*)(ws + 68321280);    // [4096][1024] fp16
    u16*  g1   = (u16*)(ws + 76709888);    // [4096][4096] fp16 (33,554,432 B) -> end 110,264,320
    float* outp = (float*)d_out;

    const dim3 blk(256);
    wconv_t_kernel<<<dim3(32, 32), blk, 0, stream>>>(Wq, wqkv, 1024, 1024);
    wconv_t_kernel<<<dim3(8, 32), blk, 0, stream>>>(Wk, wqkv + 1024 * 1024, 1024, 256);
    wconv_t_kernel<<<dim3(8, 32), blk, 0, stream>>>(Wv, wqkv + 1280 * 1024, 1024, 256);
    wconv_t_kernel<<<dim3(32, 32), blk, 0, stream>>>(Wo, wo_t, 1024, 1024);
    wconv_t_kernel<<<dim3(128, 32), blk, 0, stream>>>(W1, w1t, 1024, 4096);
    wconv_t_kernel<<<dim3(128, 32), blk, 0, stream>>>(W3, w3t, 1024, 4096);
    wconv_t_kernel<<<dim3(32, 128), blk, 0, stream>>>(W2, w2t, 4096, 1024);

    rms_in_kernel<<<dim3(NROW), blk, 0, stream>>>(x, wn, gw, hbuf);
    gemm_bt<0><<<dim3(12, 33), blk, 0, stream>>>(hbuf, wqkv, qkvb, nullptr, NROW, 1536, 1024);
    attn_kernel<<<dim3(32, 16, 2), blk, 0, stream>>>(qkvb, ctxn, hnw);
    gemm_bt<1><<<dim3(8, 32), blk, 0, stream>>>(ctxn, wo_t, yb, x, 4096, 1024, 1024);
    rms_row_kernel<<<dim3(4096), blk, 0, stream>>>(yb, wf, zb);
    gemm_bt<0><<<dim3(32, 32), blk, 0, stream>>>(zb, w1t, g1, nullptr, 4096, 4096, 1024);
    gemm_bt<2><<<dim3(32, 32), blk, 0, stream>>>(zb, w3t, g1, g1, 4096, 4096, 1024);
    gemm_bt<1><<<dim3(8, 32), blk, 0, stream>>>(g1, w2t, outp, yb, 4096, 1024, 4096);
}

// Round 13
// 477.274 us; speedup vs baseline: 1.0307x; 1.0307x over previous
//
#include <hip/hip_runtime.h>

typedef unsigned short u16;
typedef __attribute__((ext_vector_type(8))) _Float16 f16x8;
typedef __attribute__((ext_vector_type(4))) float f32x4;

// GW=16 gw tokens; per-batch seq t = 2048+16 = 2064; total rows 2*2064 = 4128.
#define TPB 2064
#define NROW 4128
#define VTS 2080   // vt padded t-stride (covers kb..kb+39 tail reads, zero-filled)

__device__ __forceinline__ u16 f2h(float f) {
    _Float16 h = (_Float16)f;
    return __builtin_bit_cast(u16, h);
}
__device__ __forceinline__ float h2f(u16 u) {
    return (float)__builtin_bit_cast(_Float16, u);
}
__device__ __forceinline__ float wave_sum(float v) {
    #pragma unroll
    for (int m = 32; m; m >>= 1) v += __shfl_xor(v, m, 64);
    return v;
}
__device__ __forceinline__ void gl_lds16(const u16* g, u16* l) {
    __builtin_amdgcn_global_load_lds((const __attribute__((address_space(1))) void*)g,
                                     (__attribute__((address_space(3))) void*)l, 16, 0, 0);
}

// ---------- weight transpose-convert: f32 [K][N] -> fp16 [N][K] ----------
__global__ __launch_bounds__(256) void wconv_t_kernel(const float* __restrict__ src,
                                                      u16* __restrict__ dst, int K, int N) {
    __shared__ float tile[32][33];
    const int k0 = blockIdx.y * 32, n0 = blockIdx.x * 32;
    const int tx = threadIdx.x & 31, ty0 = threadIdx.x >> 5;
    #pragma unroll
    for (int r = 0; r < 4; r++) {
        int ky = ty0 + r * 8;
        tile[ky][tx] = src[(size_t)(k0 + ky) * N + n0 + tx];
    }
    __syncthreads();
    #pragma unroll
    for (int r = 0; r < 4; r++) {
        int ny = ty0 + r * 8;
        dst[(size_t)(n0 + ny) * K + k0 + tx] = f2h(tile[tx][ny]);
    }
}

// ---------- V transpose: qkv V-cols -> vt[b*4+g][dv=64][VTS] fp16 (zero tail) ----------
__global__ __launch_bounds__(256) void vtrans_kernel(const u16* __restrict__ qkv,
                                                     u16* __restrict__ vt) {
    __shared__ u16 tile[32][33];
    const int bg = blockIdx.z;                 // b*4+g
    const int b = bg >> 2, g = bg & 3;
    const int t0 = blockIdx.x * 32, d0 = blockIdx.y * 32;
    const int tx = threadIdx.x & 31, ty0 = threadIdx.x >> 5;
    #pragma unroll
    for (int r = 0; r < 4; r++) {
        int t = t0 + ty0 + r * 8;
        u16 v = 0;
        if (t < TPB) v = qkv[(size_t)(b * TPB + t) * 1536 + 1280 + g * 64 + d0 + tx];
        tile[ty0 + r * 8][tx] = v;
    }
    __syncthreads();
    #pragma unroll
    for (int r = 0; r < 4; r++) {
        int d = d0 + ty0 + r * 8;
        vt[((size_t)bg * 64 + d) * VTS + t0 + tx] = tile[tx][ty0 + r * 8];
    }
}

// ---------- RMSNorm(x) + prepend RAW gw tokens (16) -> h fp16 [4128][1024] ----------
__global__ __launch_bounds__(256) void rms_in_kernel(const float* __restrict__ x,
                                                     const float* __restrict__ w,
                                                     const float* __restrict__ gwp,
                                                     u16* __restrict__ h) {
    const int r = blockIdx.x;                 // 0..4127
    const int b = r / TPB, pos = r - b * TPB;
    const int tid = threadIdx.x;
    u16* hr = h + (size_t)r * 1024;
    if (pos < 16) {                           // raw gw tokens (not normalized)
        const float* s = gwp + (size_t)pos * 1024;
        for (int c = tid; c < 1024; c += 256) hr[c] = f2h(s[c]);
        return;
    }
    const float* xr = x + ((size_t)b * 2048 + (pos - 16)) * 1024;
    float v[4]; float ss = 0.f;
    #pragma unroll
    for (int i = 0; i < 4; i++) { v[i] = xr[tid + 256 * i]; ss += v[i] * v[i]; }
    ss = wave_sum(ss);
    __shared__ float red[4];
    if ((tid & 63) == 0) red[tid >> 6] = ss;
    __syncthreads();
    float tot = red[0] + red[1] + red[2] + red[3];
    float rn = rsqrtf(tot * (1.f / 1024.f) + 1e-6f);
    #pragma unroll
    for (int i = 0; i < 4; i++) hr[tid + 256 * i] = f2h(v[i] * rn * w[tid + 256 * i]);
}

// ---------- RMSNorm(y f32 [4096][1024]) -> z fp16 ----------
__global__ __launch_bounds__(256) void rms_row_kernel(const float* __restrict__ in,
                                                      const float* __restrict__ w,
                                                      u16* __restrict__ out) {
    const int r = blockIdx.x;
    const int tid = threadIdx.x;
    const float* xr = in + (size_t)r * 1024;
    float v[4]; float ss = 0.f;
    #pragma unroll
    for (int i = 0; i < 4; i++) { v[i] = xr[tid + 256 * i]; ss += v[i] * v[i]; }
    ss = wave_sum(ss);
    __shared__ float red[4];
    if ((tid & 63) == 0) red[tid >> 6] = ss;
    __syncthreads();
    float tot = red[0] + red[1] + red[2] + red[3];
    float rn = rsqrtf(tot * (1.f / 1024.f) + 1e-6f);
    u16* orow = out + (size_t)r * 1024;
    #pragma unroll
    for (int i = 0; i < 4; i++) orow[tid + 256 * i] = f2h(v[i] * rn * w[tid + 256 * i]);
}

// ---------- GEMM C[M][N] = A[M][K] * Bt[N][K]^T  (fp16 in, m97 structure) ----------
__device__ __forceinline__ void stage_tile(const u16* __restrict__ A, const u16* __restrict__ B,
                                           u16* As, u16* Bs, int m0, int n0, int k0,
                                           int M, int K, int tid) {
    const int wb = tid & ~63;
    #pragma unroll
    for (int t = 0; t < 2; t++) {
        int seg = t * 256 + tid;
        int row = seg >> 2, kc = seg & 3;
        int ar = m0 + row; if (ar > M - 1) ar = M - 1;
        gl_lds16(A + (size_t)ar * K + k0 + kc * 8, As + (size_t)(t * 256 + wb) * 8);
        gl_lds16(B + (size_t)(n0 + row) * K + k0 + kc * 8, Bs + (size_t)(t * 256 + wb) * 8);
    }
}

template <int EPI>
__global__ __launch_bounds__(256, 2) void gemm_bt(const u16* __restrict__ A,
                                                  const u16* __restrict__ B,
                                                  void* Cout,
                                                  const void* aux,
                                                  int M, int N, int K) {
    __shared__ __align__(16) u16 As[2][4096];
    __shared__ __align__(16) u16 Bs[2][4096];
    const int tid = threadIdx.x;
    const int m0 = blockIdx.y * 128, n0 = blockIdx.x * 128;
    const int w = tid >> 6, l = tid & 63;
    const int wr = w >> 1, wc = w & 1, lr = l & 15, lg = l >> 4;
    f32x4 acc[4][4] = {};
    const int NT = K >> 5;
    stage_tile(A, B, As[0], Bs[0], m0, n0, 0, M, K, tid);
    for (int t = 0; t < NT; t++) {
        const int p = t & 1;
        __syncthreads();                       // drains vmcnt(0): staged tile ready
        if (t + 1 < NT) stage_tile(A, B, As[p ^ 1], Bs[p ^ 1], m0, n0, (t + 1) * 32, M, K, tid);
        f16x8 af[4], bf[4];
        #pragma unroll
        for (int i = 0; i < 4; i++) {
            af[i] = *(const f16x8*)&As[p][(wr * 64 + i * 16 + lr) * 32 + lg * 8];
            bf[i] = *(const f16x8*)&Bs[p][(wc * 64 + i * 16 + lr) * 32 + lg * 8];
        }
        #pragma unroll
        for (int i = 0; i < 4; i++)
            #pragma unroll
            for (int j = 0; j < 4; j++)
                acc[i][j] = __builtin_amdgcn_mfma_f32_16x16x32_f16(af[i], bf[j], acc[i][j], 0, 0, 0);
    }
    #pragma unroll
    for (int i = 0; i < 4; i++) {
        const int rowb = m0 + wr * 64 + i * 16 + lg * 4;
        #pragma unroll
        for (int j = 0; j < 4; j++) {
            const int col = n0 + wc * 64 + j * 16 + lr;
            #pragma unroll
            for (int e = 0; e < 4; e++) {
                const int r2 = rowb + e;
                if (r2 < M) {
                    const size_t idx = (size_t)r2 * N + col;
                    const float v = acc[i][j][e];
                    if constexpr (EPI == 0) {
                        ((u16*)Cout)[idx] = f2h(v);
                    } else if constexpr (EPI == 1) {
                        ((float*)Cout)[idx] = v + ((const float*)aux)[idx];
                    } else {
                        float t0 = h2f(((const u16*)aux)[idx]);
                        float s = t0 / (1.f + __expf(-t0));
                        ((u16*)Cout)[idx] = f2h(s * v);
                    }
                }
            }
        }
    }
}

// ---------- flash attention (swapped QK^T, GQA, fused head-RMSNorm), GW=16 ----------
// qkv: fp16 [b*2064][1536]; vt: V^T [b*4+g][64][VTS]; causal kv <= qpos.
__global__ __launch_bounds__(256) void attn_kernel(const u16* __restrict__ qkv,
                                                   const u16* __restrict__ vt,
                                                   u16* __restrict__ ctxn,
                                                   const float* __restrict__ hnw) {
    const int qt = blockIdx.x, h = blockIdx.y, b = blockIdx.z;
    const int wv = threadIdx.x >> 6, l = threadIdx.x & 63;
    const int lr = l & 15, lg = l >> 4;
    const int g = h >> 2;
    const int orow0 = qt * 64 + wv * 16;
    const int qpos0 = 16 + orow0;
    const int qpos = qpos0 + lr;           // this lane's q row (S^T col layout)
    const int RS = 1536;
    const int LASTROW = TPB - 1;           // 2063

    const u16* qbase = qkv + (size_t)(b * TPB + qpos) * RS + h * 64;
    const f16x8 qf0 = *(const f16x8*)(qbase + lg * 8);
    const f16x8 qf1 = *(const f16x8*)(qbase + 32 + lg * 8);
    const u16* vtb = vt + (size_t)(b * 4 + g) * 64 * VTS;

    float m = -INFINITY, lsum = 0.f;
    f32x4 oc[4] = {};

    const int sig = 8 * (lr >> 2) + (lr & 3);   // sigma0 row permutation
    const int NT = ((qpos0 + 15) >> 5) + 1;
    for (int kt = 0; kt < NT; kt++) {
        const int kb = kt * 32;
        int kv0 = kb + sig;     int kv0c = kv0 > LASTROW ? LASTROW : kv0;
        int kv1 = kv0 + 4;      int kv1c = kv1 > LASTROW ? LASTROW : kv1;
        const u16* kr0 = qkv + (size_t)(b * TPB + kv0c) * RS + 1024 + g * 64;
        const u16* kr1 = qkv + (size_t)(b * TPB + kv1c) * RS + 1024 + g * 64;
        const f16x8 a0  = *(const f16x8*)(kr0 + lg * 8);
        const f16x8 a0b = *(const f16x8*)(kr0 + 32 + lg * 8);
        const f16x8 a1  = *(const f16x8*)(kr1 + lg * 8);
        const f16x8 a1b = *(const f16x8*)(kr1 + 32 + lg * 8);
        // V fragments: vectorized from V^T (independent of softmax -> issue early)
        f16x8 vf[4];
        #pragma unroll
        for (int dt = 0; dt < 4; dt++)
            vf[dt] = *(const f16x8*)&vtb[(size_t)(dt * 16 + lr) * VTS + kb + lg * 8];
        f32x4 st0 = {}, st1 = {};
        st0 = __builtin_amdgcn_mfma_f32_16x16x32_f16(a0,  qf0, st0, 0, 0, 0);
        st0 = __builtin_amdgcn_mfma_f32_16x16x32_f16(a0b, qf1, st0, 0, 0, 0);
        st1 = __builtin_amdgcn_mfma_f32_16x16x32_f16(a1,  qf0, st1, 0, 0, 0);
        st1 = __builtin_amdgcn_mfma_f32_16x16x32_f16(a1b, qf1, st1, 0, 0, 0);
        // lane holds S[q=qpos][kv=kb+8*lg+j] (st0) and kv+4 (st1)
        float sv[8]; float bm = -INFINITY;
        #pragma unroll
        for (int j = 0; j < 4; j++) {
            const int kva = kb + 8 * lg + j;
            float s0 = st0[j] * 0.125f; if (kva > qpos) s0 = -INFINITY;
            float s1 = st1[j] * 0.125f; if (kva + 4 > qpos) s1 = -INFINITY;
            sv[j] = s0; sv[4 + j] = s1;
            bm = fmaxf(bm, fmaxf(s0, s1));
        }
        bm = fmaxf(bm, __shfl_xor(bm, 16, 64));
        bm = fmaxf(bm, __shfl_xor(bm, 32, 64));
        // defer-max (T13): only rescale when some row's max grew past threshold
        if (!__all(bm - m <= 8.f)) {
            const float nm = fmaxf(m, bm);
            const float sc = __expf(m - nm);
            m = nm;
            lsum *= sc;
            float scj[4];
            #pragma unroll
            for (int j = 0; j < 4; j++) scj[j] = __shfl(sc, 4 * lg + j, 64);
            #pragma unroll
            for (int dt = 0; dt < 4; dt++)
                #pragma unroll
                for (int j = 0; j < 4; j++) oc[dt][j] *= scj[j];
        }
        float ps = 0.f;
        f16x8 pa;
        #pragma unroll
        for (int j = 0; j < 8; j++) {
            float p = __expf(sv[j] - m);       // masked -> 0; bounded by e^8
            ps += p;
            pa[j] = (_Float16)p;
        }
        ps += __shfl_xor(ps, 16, 64); ps += __shfl_xor(ps, 32, 64);
        lsum += ps;
        #pragma unroll
        for (int dt = 0; dt < 4; dt++)
            oc[dt] = __builtin_amdgcn_mfma_f32_16x16x32_f16(pa, vf[dt], oc[dt], 0, 0, 0);
    }
    // epilogue: /l, head RMSNorm over dv=64, * head_norm_w, store fp16
    float lj[4];
    #pragma unroll
    for (int j = 0; j < 4; j++) lj[j] = __shfl(lsum, 4 * lg + j, 64);
    float o[4][4]; float ssq[4] = {0, 0, 0, 0};
    #pragma unroll
    for (int dt = 0; dt < 4; dt++)
        #pragma unroll
        for (int j = 0; j < 4; j++) {
            float v = oc[dt][j] / lj[j];
            o[dt][j] = v; ssq[j] += v * v;
        }
    float rj[4];
    #pragma unroll
    for (int j = 0; j < 4; j++) {
        float s = ssq[j];
        s += __shfl_xor(s, 1, 64); s += __shfl_xor(s, 2, 64);
        s += __shfl_xor(s, 4, 64); s += __shfl_xor(s, 8, 64);
        rj[j] = rsqrtf(s * (1.f / 64.f) + 1e-6f);
    }
    #pragma unroll
    for (int dt = 0; dt < 4; dt++) {
        const float hw = hnw[h * 64 + dt * 16 + lr];
        #pragma unroll
        for (int j = 0; j < 4; j++) {
            const int orow = orow0 + 4 * lg + j;
            ctxn[(size_t)(b * 2048 + orow) * 1024 + h * 64 + dt * 16 + lr] =
                f2h(o[dt][j] * rj[j] * hw);
        }
    }
}

extern "C" void kernel_launch(void* const* d_in, const int* in_sizes, int n_in,
                              void* d_out, int out_size, void* d_ws, size_t ws_size,
                              hipStream_t stream) {
    const float* x   = (const float*)d_in[0];
    const float* wn  = (const float*)d_in[1];
    const float* gw  = (const float*)d_in[2];
    const float* Wq  = (const float*)d_in[3];
    const float* Wk  = (const float*)d_in[4];
    const float* Wv  = (const float*)d_in[5];
    const float* Wo  = (const float*)d_in[6];
    const float* hnw = (const float*)d_in[7];
    const float* wf  = (const float*)d_in[8];
    const float* W1  = (const float*)d_in[9];
    const float* W3  = (const float*)d_in[10];
    const float* W2  = (const float*)d_in[11];

    char* ws = (char*)d_ws;
    u16*  wqkv = (u16*)(ws + 0);           // [1536][1024] fp16
    u16*  wo_t = (u16*)(ws + 3145728);     // [1024][1024]
    u16*  w1t  = (u16*)(ws + 5242880);     // [4096][1024]
    u16*  w3t  = (u16*)(ws + 13631488);    // [4096][1024]
    u16*  w2t  = (u16*)(ws + 22020096);    // [1024][4096]
    u16*  hbuf = (u16*)(ws + 30408704);    // [4128][1024] fp16
    u16*  qkvb = (u16*)(ws + 38862848);    // [4128][1536] fp16
    u16*  ctxn = hbuf;                     // [4096][1024] overlays hbuf (dead after QKV)
    float* yb  = (float*)(ws + 51544064);  // [4096][1024] f32
    u16*  zb   = (u16*)(ws + 68321280);    // [4096][1024] fp16
    u16*  g1   = (u16*)(ws + 76709888);    // [4096][4096] fp16
    u16*  vt   = (u16*)(ws + 110264320);   // [8][64][2080] fp16 (2,129,920 B) -> end 112,394,240
    float* outp = (float*)d_out;

    const dim3 blk(256);
    wconv_t_kernel<<<dim3(32, 32), blk, 0, stream>>>(Wq, wqkv, 1024, 1024);
    wconv_t_kernel<<<dim3(8, 32), blk, 0, stream>>>(Wk, wqkv + 1024 * 1024, 1024, 256);
    wconv_t_kernel<<<dim3(8, 32), blk, 0, stream>>>(Wv, wqkv + 1280 * 1024, 1024, 256);
    wconv_t_kernel<<<dim3(32, 32), blk, 0, stream>>>(Wo, wo_t, 1024, 1024);
    wconv_t_kernel<<<dim3(128, 32), blk, 0, stream>>>(W1, w1t, 1024, 4096);
    wconv_t_kernel<<<dim3(128, 32), blk, 0, stream>>>(W3, w3t, 1024, 4096);
    wconv_t_kernel<<<dim3(32, 128), blk, 0, stream>>>(W2, w2t, 4096, 1024);

    rms_in_kernel<<<dim3(NROW), blk, 0, stream>>>(x, wn, gw, hbuf);
    gemm_bt<0><<<dim3(12, 33), blk, 0, stream>>>(hbuf, wqkv, qkvb, nullptr, NROW, 1536, 1024);
    vtrans_kernel<<<dim3(65, 2, 8), blk, 0, stream>>>(qkvb, vt);
    attn_kernel<<<dim3(32, 16, 2), blk, 0, stream>>>(qkvb, vt, ctxn, hnw);
    gemm_bt<1><<<dim3(8, 32), blk, 0, stream>>>(ctxn, wo_t, yb, x, 4096, 1024, 1024);
    rms_row_kernel<<<dim3(4096), blk, 0, stream>>>(yb, wf, zb);
    gemm_bt<0><<<dim3(32, 32), blk, 0, stream>>>(zb, w1t, g1, nullptr, 4096, 4096, 1024);
    gemm_bt<2><<<dim3(32, 32), blk, 0, stream>>>(zb, w3t, g1, g1, 4096, 4096, 1024);
    gemm_bt<1><<<dim3(8, 32), blk, 0, stream>>>(g1, w2t, outp, yb, 4096, 1024, 4096);
}

// Round 14
// 368.741 us; speedup vs baseline: 1.3340x; 1.2943x over previous
//
#include <hip/hip_runtime.h>

typedef unsigned short u16;
typedef __attribute__((ext_vector_type(8))) _Float16 f16x8;
typedef __attribute__((ext_vector_type(4))) float f32x4;

// GW=16 gw tokens; per-batch seq t = 2048+16 = 2064; total rows 2*2064 = 4128.
#define TPB 2064
#define NROW 4128
#define VTS 2080   // vt padded t-stride (zero tail)

__device__ __forceinline__ u16 f2h(float f) {
    _Float16 h = (_Float16)f;
    return __builtin_bit_cast(u16, h);
}
__device__ __forceinline__ float h2f(u16 u) {
    return (float)__builtin_bit_cast(_Float16, u);
}
__device__ __forceinline__ float wave_sum(float v) {
    #pragma unroll
    for (int m = 32; m; m >>= 1) v += __shfl_xor(v, m, 64);
    return v;
}
__device__ __forceinline__ void gl_lds16(const u16* g, u16* l) {
    __builtin_amdgcn_global_load_lds((const __attribute__((address_space(1))) void*)g,
                                     (__attribute__((address_space(3))) void*)l, 16, 0, 0);
}

// ---------- weight transpose-convert: f32 [K][N] -> fp16 [N][K] ----------
__global__ __launch_bounds__(256) void wconv_t_kernel(const float* __restrict__ src,
                                                      u16* __restrict__ dst, int K, int N) {
    __shared__ float tile[32][33];
    const int k0 = blockIdx.y * 32, n0 = blockIdx.x * 32;
    const int tx = threadIdx.x & 31, ty0 = threadIdx.x >> 5;
    #pragma unroll
    for (int r = 0; r < 4; r++) {
        int ky = ty0 + r * 8;
        tile[ky][tx] = src[(size_t)(k0 + ky) * N + n0 + tx];
    }
    __syncthreads();
    #pragma unroll
    for (int r = 0; r < 4; r++) {
        int ny = ty0 + r * 8;
        dst[(size_t)(n0 + ny) * K + k0 + tx] = f2h(tile[tx][ny]);
    }
}

// ---------- V transpose: qkv V-cols -> vt[b*4+g][dv=64][VTS] fp16 (zero tail) ----------
__global__ __launch_bounds__(256) void vtrans_kernel(const u16* __restrict__ qkv,
                                                     u16* __restrict__ vt) {
    __shared__ u16 tile[32][33];
    const int bg = blockIdx.z;                 // b*4+g
    const int b = bg >> 2, g = bg & 3;
    const int t0 = blockIdx.x * 32, d0 = blockIdx.y * 32;
    const int tx = threadIdx.x & 31, ty0 = threadIdx.x >> 5;
    #pragma unroll
    for (int r = 0; r < 4; r++) {
        int t = t0 + ty0 + r * 8;
        u16 v = 0;
        if (t < TPB) v = qkv[(size_t)(b * TPB + t) * 1536 + 1280 + g * 64 + d0 + tx];
        tile[ty0 + r * 8][tx] = v;
    }
    __syncthreads();
    #pragma unroll
    for (int r = 0; r < 4; r++) {
        int d = d0 + ty0 + r * 8;
        vt[((size_t)bg * 64 + d) * VTS + t0 + tx] = tile[tx][ty0 + r * 8];
    }
}

// ---------- RMSNorm(x) + prepend RAW gw tokens (16) -> h fp16 [4128][1024] ----------
__global__ __launch_bounds__(256) void rms_in_kernel(const float* __restrict__ x,
                                                     const float* __restrict__ w,
                                                     const float* __restrict__ gwp,
                                                     u16* __restrict__ h) {
    const int r = blockIdx.x;                 // 0..4127
    const int b = r / TPB, pos = r - b * TPB;
    const int tid = threadIdx.x;
    u16* hr = h + (size_t)r * 1024;
    if (pos < 16) {                           // raw gw tokens (not normalized)
        const float* s = gwp + (size_t)pos * 1024;
        for (int c = tid; c < 1024; c += 256) hr[c] = f2h(s[c]);
        return;
    }
    const float* xr = x + ((size_t)b * 2048 + (pos - 16)) * 1024;
    float v[4]; float ss = 0.f;
    #pragma unroll
    for (int i = 0; i < 4; i++) { v[i] = xr[tid + 256 * i]; ss += v[i] * v[i]; }
    ss = wave_sum(ss);
    __shared__ float red[4];
    if ((tid & 63) == 0) red[tid >> 6] = ss;
    __syncthreads();
    float tot = red[0] + red[1] + red[2] + red[3];
    float rn = rsqrtf(tot * (1.f / 1024.f) + 1e-6f);
    #pragma unroll
    for (int i = 0; i < 4; i++) hr[tid + 256 * i] = f2h(v[i] * rn * w[tid + 256 * i]);
}

// ---------- RMSNorm(y f32 [4096][1024]) -> z fp16 ----------
__global__ __launch_bounds__(256) void rms_row_kernel(const float* __restrict__ in,
                                                      const float* __restrict__ w,
                                                      u16* __restrict__ out) {
    const int r = blockIdx.x;
    const int tid = threadIdx.x;
    const float* xr = in + (size_t)r * 1024;
    float v[4]; float ss = 0.f;
    #pragma unroll
    for (int i = 0; i < 4; i++) { v[i] = xr[tid + 256 * i]; ss += v[i] * v[i]; }
    ss = wave_sum(ss);
    __shared__ float red[4];
    if ((tid & 63) == 0) red[tid >> 6] = ss;
    __syncthreads();
    float tot = red[0] + red[1] + red[2] + red[3];
    float rn = rsqrtf(tot * (1.f / 1024.f) + 1e-6f);
    u16* orow = out + (size_t)r * 1024;
    #pragma unroll
    for (int i = 0; i < 4; i++) orow[tid + 256 * i] = f2h(v[i] * rn * w[tid + 256 * i]);
}

// ---------- GEMM C[M][N] = A[M][K] * Bt[N][K]^T  (fp16 in, m97 structure) ----------
__device__ __forceinline__ void stage_tile(const u16* __restrict__ A, const u16* __restrict__ B,
                                           u16* As, u16* Bs, int m0, int n0, int k0,
                                           int M, int K, int tid) {
    const int wb = tid & ~63;
    #pragma unroll
    for (int t = 0; t < 2; t++) {
        int seg = t * 256 + tid;
        int row = seg >> 2, kc = seg & 3;
        int ar = m0 + row; if (ar > M - 1) ar = M - 1;
        gl_lds16(A + (size_t)ar * K + k0 + kc * 8, As + (size_t)(t * 256 + wb) * 8);
        gl_lds16(B + (size_t)(n0 + row) * K + k0 + kc * 8, Bs + (size_t)(t * 256 + wb) * 8);
    }
}

template <int EPI>
__global__ __launch_bounds__(256, 2) void gemm_bt(const u16* __restrict__ A,
                                                  const u16* __restrict__ B,
                                                  void* Cout,
                                                  const void* aux,
                                                  int M, int N, int K) {
    __shared__ __align__(16) u16 As[2][4096];
    __shared__ __align__(16) u16 Bs[2][4096];
    const int tid = threadIdx.x;
    const int m0 = blockIdx.y * 128, n0 = blockIdx.x * 128;
    const int w = tid >> 6, l = tid & 63;
    const int wr = w >> 1, wc = w & 1, lr = l & 15, lg = l >> 4;
    f32x4 acc[4][4] = {};
    const int NT = K >> 5;
    stage_tile(A, B, As[0], Bs[0], m0, n0, 0, M, K, tid);
    for (int t = 0; t < NT; t++) {
        const int p = t & 1;
        __syncthreads();                       // drains vmcnt(0): staged tile ready
        if (t + 1 < NT) stage_tile(A, B, As[p ^ 1], Bs[p ^ 1], m0, n0, (t + 1) * 32, M, K, tid);
        f16x8 af[4], bf[4];
        #pragma unroll
        for (int i = 0; i < 4; i++) {
            af[i] = *(const f16x8*)&As[p][(wr * 64 + i * 16 + lr) * 32 + lg * 8];
            bf[i] = *(const f16x8*)&Bs[p][(wc * 64 + i * 16 + lr) * 32 + lg * 8];
        }
        #pragma unroll
        for (int i = 0; i < 4; i++)
            #pragma unroll
            for (int j = 0; j < 4; j++)
                acc[i][j] = __builtin_amdgcn_mfma_f32_16x16x32_f16(af[i], bf[j], acc[i][j], 0, 0, 0);
    }
    #pragma unroll
    for (int i = 0; i < 4; i++) {
        const int rowb = m0 + wr * 64 + i * 16 + lg * 4;
        #pragma unroll
        for (int j = 0; j < 4; j++) {
            const int col = n0 + wc * 64 + j * 16 + lr;
            #pragma unroll
            for (int e = 0; e < 4; e++) {
                const int r2 = rowb + e;
                if (r2 < M) {
                    const size_t idx = (size_t)r2 * N + col;
                    const float v = acc[i][j][e];
                    if constexpr (EPI == 0) {
                        ((u16*)Cout)[idx] = f2h(v);
                    } else if constexpr (EPI == 1) {
                        ((float*)Cout)[idx] = v + ((const float*)aux)[idx];
                    } else {
                        float t0 = h2f(((const u16*)aux)[idx]);
                        float s = t0 / (1.f + __expf(-t0));
                        ((u16*)Cout)[idx] = f2h(s * v);
                    }
                }
            }
        }
    }
}

// ---------- flash attention: block = (fold-qt, g, b); 4 waves = 4 heads of group g ----------
// K tile [32 rows][64 dk] and V^T tile [64 dv][32 kv] LDS-staged (double-buffered,
// XOR-swizzled via pre-swizzled global source). Causal kv <= qpos; gw keys 0..15 free.
__global__ __launch_bounds__(256) void attn_kernel(const u16* __restrict__ qkv,
                                                   const u16* __restrict__ vt,
                                                   u16* __restrict__ ctxn,
                                                   const float* __restrict__ hnw) {
    __shared__ __align__(16) u16 Ks[2][2048];   // [32][8 segs][8 halves], seg^=swz(row)
    __shared__ __align__(16) u16 Vs[2][2048];   // [64][4 slots][8 halves], slot^=vswz(dv)
    const int bx = blockIdx.x, g = blockIdx.y, b = blockIdx.z;
    const int tid = threadIdx.x;
    const int w = tid >> 6, l = tid & 63;
    const int lr = l & 15, lg = l >> 4;
    const int h = g * 4 + w;                    // wave = head within group
    const int sig = 8 * (lr >> 2) + (lr & 3);   // sigma0 row permutation
    const int LASTROW = TPB - 1;
    const u16* vtb = vt + (size_t)(b * 4 + g) * 64 * VTS;
    const u16* kbase = qkv + (size_t)b * TPB * 1536 + 1024 + g * 64;

    // staging lane constants (source pre-swizzle, linear LDS dest)
    const int krow = tid >> 3;                                   // 0..31
    const int ksrc = (tid & 7) ^ ((krow & 3) | (((krow >> 3) & 1) << 2));
    const int vdv = tid >> 2;                                    // 0..63
    const int vsrc = (tid & 3) ^ ((vdv >> 1) & 3);
    const int wb8 = (tid & ~63) * 8;                             // wave-uniform LDS base

    // read-side swizzled fragment offsets (halves)
    const int swzr = (sig & 3) | (((sig >> 3) & 1) << 2);        // same for sig and sig+4
    const int ka0  = sig * 64 + ((lg ^ swzr) << 3);
    const int ka0b = sig * 64 + (((lg + 4) ^ swzr) << 3);
    const int ka1  = (sig + 4) * 64 + ((lg ^ swzr) << 3);
    const int ka1b = (sig + 4) * 64 + (((lg + 4) ^ swzr) << 3);
    int kv_off[4];
    #pragma unroll
    for (int dt = 0; dt < 4; dt++) {
        const int dv = dt * 16 + lr;
        kv_off[dt] = dv * 32 + ((lg ^ ((dv >> 1) & 3)) << 3);
    }

    const float hw0 = hnw[h * 64 + 0 * 16 + lr];
    const float hw1 = hnw[h * 64 + 1 * 16 + lr];
    const float hw2 = hnw[h * 64 + 2 * 16 + lr];
    const float hw3 = hnw[h * 64 + 3 * 16 + lr];

    for (int half = 0; half < 2; half++) {
        const int qt = half ? (127 - bx) : bx;   // fold balance: NT(lo)+NT(hi) ~ const
        const int orow0 = qt * 16;
        const int qpos0 = 16 + orow0;
        const int qpos = qpos0 + lr;
        const u16* qbase = qkv + (size_t)(b * TPB + qpos) * 1536 + h * 64;
        const f16x8 qf0 = *(const f16x8*)(qbase + lg * 8);
        const f16x8 qf1 = *(const f16x8*)(qbase + 32 + lg * 8);

        float m = -INFINITY, lsum = 0.f;
        f32x4 oc[4] = {};
        const int NT = ((qpos0 + 15) >> 5) + 1;

        __syncthreads();                         // protect LDS reuse across halves
        // prologue: stage kt=0 into buf 0
        gl_lds16(kbase + (size_t)krow * 1536 + ksrc * 8, Ks[0] + wb8);
        gl_lds16(vtb + (size_t)vdv * VTS + vsrc * 8, Vs[0] + wb8);

        for (int kt = 0; kt < NT; kt++) {
            const int p = kt & 1;
            const int kb = kt * 32;
            __syncthreads();                     // buf[p] staged (vmcnt drained)
            if (kt + 1 < NT) {
                const int kb2 = kb + 32;
                int kr = kb2 + krow; if (kr > LASTROW) kr = LASTROW;
                gl_lds16(kbase + (size_t)kr * 1536 + ksrc * 8, Ks[p ^ 1] + wb8);
                gl_lds16(vtb + (size_t)vdv * VTS + kb2 + vsrc * 8, Vs[p ^ 1] + wb8);
            }
            const f16x8 a0  = *(const f16x8*)&Ks[p][ka0];
            const f16x8 a0b = *(const f16x8*)&Ks[p][ka0b];
            const f16x8 a1  = *(const f16x8*)&Ks[p][ka1];
            const f16x8 a1b = *(const f16x8*)&Ks[p][ka1b];
            f16x8 vf[4];
            #pragma unroll
            for (int dt = 0; dt < 4; dt++) vf[dt] = *(const f16x8*)&Vs[p][kv_off[dt]];

            f32x4 st0 = {}, st1 = {};
            st0 = __builtin_amdgcn_mfma_f32_16x16x32_f16(a0,  qf0, st0, 0, 0, 0);
            st0 = __builtin_amdgcn_mfma_f32_16x16x32_f16(a0b, qf1, st0, 0, 0, 0);
            st1 = __builtin_amdgcn_mfma_f32_16x16x32_f16(a1,  qf0, st1, 0, 0, 0);
            st1 = __builtin_amdgcn_mfma_f32_16x16x32_f16(a1b, qf1, st1, 0, 0, 0);

            float sv[8]; float bm = -INFINITY;
            if (kb + 31 <= qpos0) {              // interior tile: no causal masking
                #pragma unroll
                for (int j = 0; j < 4; j++) {
                    sv[j] = st0[j] * 0.125f;
                    sv[4 + j] = st1[j] * 0.125f;
                    bm = fmaxf(bm, fmaxf(sv[j], sv[4 + j]));
                }
            } else {
                #pragma unroll
                for (int j = 0; j < 4; j++) {
                    const int kva = kb + 8 * lg + j;
                    float s0 = st0[j] * 0.125f; if (kva > qpos) s0 = -INFINITY;
                    float s1 = st1[j] * 0.125f; if (kva + 4 > qpos) s1 = -INFINITY;
                    sv[j] = s0; sv[4 + j] = s1;
                    bm = fmaxf(bm, fmaxf(s0, s1));
                }
            }
            bm = fmaxf(bm, __shfl_xor(bm, 16, 64));
            bm = fmaxf(bm, __shfl_xor(bm, 32, 64));
            if (!__all(bm - m <= 8.f)) {         // defer-max (T13)
                const float nm = fmaxf(m, bm);
                const float sc = __expf(m - nm);
                m = nm;
                lsum *= sc;
                float scj[4];
                #pragma unroll
                for (int j = 0; j < 4; j++) scj[j] = __shfl(sc, 4 * lg + j, 64);
                #pragma unroll
                for (int dt = 0; dt < 4; dt++)
                    #pragma unroll
                    for (int j = 0; j < 4; j++) oc[dt][j] *= scj[j];
            }
            float ps = 0.f;
            f16x8 pa;
            #pragma unroll
            for (int j = 0; j < 8; j++) {
                float p2 = __expf(sv[j] - m);    // masked -> 0; bounded by e^8
                ps += p2;
                pa[j] = (_Float16)p2;
            }
            ps += __shfl_xor(ps, 16, 64); ps += __shfl_xor(ps, 32, 64);
            lsum += ps;
            #pragma unroll
            for (int dt = 0; dt < 4; dt++)
                oc[dt] = __builtin_amdgcn_mfma_f32_16x16x32_f16(pa, vf[dt], oc[dt], 0, 0, 0);
        }
        // epilogue: /l, head RMSNorm over dv=64, * head_norm_w, store fp16
        float lj[4];
        #pragma unroll
        for (int j = 0; j < 4; j++) lj[j] = __shfl(lsum, 4 * lg + j, 64);
        float o[4][4]; float ssq[4] = {0, 0, 0, 0};
        #pragma unroll
        for (int dt = 0; dt < 4; dt++)
            #pragma unroll
            for (int j = 0; j < 4; j++) {
                float v = oc[dt][j] / lj[j];
                o[dt][j] = v; ssq[j] += v * v;
            }
        float rj[4];
        #pragma unroll
        for (int j = 0; j < 4; j++) {
            float s = ssq[j];
            s += __shfl_xor(s, 1, 64); s += __shfl_xor(s, 2, 64);
            s += __shfl_xor(s, 4, 64); s += __shfl_xor(s, 8, 64);
            rj[j] = rsqrtf(s * (1.f / 64.f) + 1e-6f);
        }
        const float hwv[4] = {hw0, hw1, hw2, hw3};
        #pragma unroll
        for (int dt = 0; dt < 4; dt++) {
            #pragma unroll
            for (int j = 0; j < 4; j++) {
                const int orow = orow0 + 4 * lg + j;
                ctxn[(size_t)(b * 2048 + orow) * 1024 + h * 64 + dt * 16 + lr] =
                    f2h(o[dt][j] * rj[j] * hwv[dt]);
            }
        }
    }
}

extern "C" void kernel_launch(void* const* d_in, const int* in_sizes, int n_in,
                              void* d_out, int out_size, void* d_ws, size_t ws_size,
                              hipStream_t stream) {
    const float* x   = (const float*)d_in[0];
    const float* wn  = (const float*)d_in[1];
    const float* gw  = (const float*)d_in[2];
    const float* Wq  = (const float*)d_in[3];
    const float* Wk  = (const float*)d_in[4];
    const float* Wv  = (const float*)d_in[5];
    const float* Wo  = (const float*)d_in[6];
    const float* hnw = (const float*)d_in[7];
    const float* wf  = (const float*)d_in[8];
    const float* W1  = (const float*)d_in[9];
    const float* W3  = (const float*)d_in[10];
    const float* W2  = (const float*)d_in[11];

    char* ws = (char*)d_ws;
    u16*  wqkv = (u16*)(ws + 0);           // [1536][1024] fp16
    u16*  wo_t = (u16*)(ws + 3145728);     // [1024][1024]
    u16*  w1t  = (u16*)(ws + 5242880);     // [4096][1024]
    u16*  w3t  = (u16*)(ws + 13631488);    // [4096][1024]
    u16*  w2t  = (u16*)(ws + 22020096);    // [1024][4096]
    u16*  hbuf = (u16*)(ws + 30408704);    // [4128][1024] fp16
    u16*  qkvb = (u16*)(ws + 38862848);    // [4128][1536] fp16
    u16*  ctxn = hbuf;                     // [4096][1024] overlays hbuf (dead after QKV)
    float* yb  = (float*)(ws + 51544064);  // [4096][1024] f32
    u16*  zb   = (u16*)(ws + 68321280);    // [4096][1024] fp16
    u16*  g1   = (u16*)(ws + 76709888);    // [4096][4096] fp16
    u16*  vt   = (u16*)(ws + 110264320);   // [8][64][2080] fp16 -> end 112,394,240
    float* outp = (float*)d_out;

    const dim3 blk(256);
    wconv_t_kernel<<<dim3(32, 32), blk, 0, stream>>>(Wq, wqkv, 1024, 1024);
    wconv_t_kernel<<<dim3(8, 32), blk, 0, stream>>>(Wk, wqkv + 1024 * 1024, 1024, 256);
    wconv_t_kernel<<<dim3(8, 32), blk, 0, stream>>>(Wv, wqkv + 1280 * 1024, 1024, 256);
    wconv_t_kernel<<<dim3(32, 32), blk, 0, stream>>>(Wo, wo_t, 1024, 1024);
    wconv_t_kernel<<<dim3(128, 32), blk, 0, stream>>>(W1, w1t, 1024, 4096);
    wconv_t_kernel<<<dim3(128, 32), blk, 0, stream>>>(W3, w3t, 1024, 4096);
    wconv_t_kernel<<<dim3(32, 128), blk, 0, stream>>>(W2, w2t, 4096, 1024);

    rms_in_kernel<<<dim3(NROW), blk, 0, stream>>>(x, wn, gw, hbuf);
    gemm_bt<0><<<dim3(12, 33), blk, 0, stream>>>(hbuf, wqkv, qkvb, nullptr, NROW, 1536, 1024);
    vtrans_kernel<<<dim3(65, 2, 8), blk, 0, stream>>>(qkvb, vt);
    attn_kernel<<<dim3(64, 4, 2), blk, 0, stream>>>(qkvb, vt, ctxn, hnw);
    gemm_bt<1><<<dim3(8, 32), blk, 0, stream>>>(ctxn, wo_t, yb, x, 4096, 1024, 1024);
    rms_row_kernel<<<dim3(4096), blk, 0, stream>>>(yb, wf, zb);
    gemm_bt<0><<<dim3(32, 32), blk, 0, stream>>>(zb, w1t, g1, nullptr, 4096, 4096, 1024);
    gemm_bt<2><<<dim3(32, 32), blk, 0, stream>>>(zb, w3t, g1, g1, 4096, 4096, 1024);
    gemm_bt<1><<<dim3(8, 32), blk, 0, stream>>>(g1, w2t, outp, yb, 4096, 1024, 4096);
}

// Round 15
// 345.723 us; speedup vs baseline: 1.4228x; 1.0666x over previous
//
#include <hip/hip_runtime.h>

typedef unsigned short u16;
typedef __attribute__((ext_vector_type(8))) _Float16 f16x8;
typedef __attribute__((ext_vector_type(4))) float f32x4;

// GW=16 gw tokens; per-batch seq t = 2048+16 = 2064; total rows 2*2064 = 4128.
#define TPB 2064
#define NROW 4128
#define VTS 2080   // vt padded t-stride (zero tail)

__device__ __forceinline__ u16 f2h(float f) {
    _Float16 h = (_Float16)f;
    return __builtin_bit_cast(u16, h);
}
__device__ __forceinline__ float h2f(u16 u) {
    return (float)__builtin_bit_cast(_Float16, u);
}
__device__ __forceinline__ float wave_sum(float v) {
    #pragma unroll
    for (int m = 32; m; m >>= 1) v += __shfl_xor(v, m, 64);
    return v;
}
__device__ __forceinline__ void gl_lds16(const u16* g, u16* l) {
    __builtin_amdgcn_global_load_lds((const __attribute__((address_space(1))) void*)g,
                                     (__attribute__((address_space(3))) void*)l, 16, 0, 0);
}

// ---------- weight transpose-convert: f32 [K][N] -> fp16 [N][K] ----------
__global__ __launch_bounds__(256) void wconv_t_kernel(const float* __restrict__ src,
                                                      u16* __restrict__ dst, int K, int N) {
    __shared__ float tile[32][33];
    const int k0 = blockIdx.y * 32, n0 = blockIdx.x * 32;
    const int tx = threadIdx.x & 31, ty0 = threadIdx.x >> 5;
    #pragma unroll
    for (int r = 0; r < 4; r++) {
        int ky = ty0 + r * 8;
        tile[ky][tx] = src[(size_t)(k0 + ky) * N + n0 + tx];
    }
    __syncthreads();
    #pragma unroll
    for (int r = 0; r < 4; r++) {
        int ny = ty0 + r * 8;
        dst[(size_t)(n0 + ny) * K + k0 + tx] = f2h(tile[tx][ny]);
    }
}

// ---------- packed W1|W3 convert: f32 [1024][4096] x2 -> fp16 w13t [8192][1024] ----------
// Packed row p: group=p>>5 (16 u-cols), w=(p>>4)&1 (0=W1,1=W3), i=p&15; feature f=group*16+i.
__global__ __launch_bounds__(256) void wconv_pack13_kernel(const float* __restrict__ W1,
                                                           const float* __restrict__ W3,
                                                           u16* __restrict__ dst) {
    __shared__ float t1[32][33];
    __shared__ float t3[32][33];
    const int f0 = blockIdx.x * 32, k0 = blockIdx.y * 32;
    const int tx = threadIdx.x & 31, ty0 = threadIdx.x >> 5;
    #pragma unroll
    for (int r = 0; r < 4; r++) {
        int ky = ty0 + r * 8;
        t1[ky][tx] = W1[(size_t)(k0 + ky) * 4096 + f0 + tx];
        t3[ky][tx] = W3[(size_t)(k0 + ky) * 4096 + f0 + tx];
    }
    __syncthreads();
    #pragma unroll
    for (int r = 0; r < 4; r++) {
        int fy = ty0 + r * 8;
        int f = f0 + fy;
        int p1 = (f >> 4) * 32 + (f & 15);
        dst[(size_t)p1 * 1024 + k0 + tx] = f2h(t1[tx][fy]);
        dst[(size_t)(p1 + 16) * 1024 + k0 + tx] = f2h(t3[tx][fy]);
    }
}

// ---------- V transpose: qkv V-cols -> vt[b*4+g][dv=64][VTS] fp16 (zero tail) ----------
__global__ __launch_bounds__(256) void vtrans_kernel(const u16* __restrict__ qkv,
                                                     u16* __restrict__ vt) {
    __shared__ u16 tile[32][33];
    const int bg = blockIdx.z;                 // b*4+g
    const int b = bg >> 2, g = bg & 3;
    const int t0 = blockIdx.x * 32, d0 = blockIdx.y * 32;
    const int tx = threadIdx.x & 31, ty0 = threadIdx.x >> 5;
    #pragma unroll
    for (int r = 0; r < 4; r++) {
        int t = t0 + ty0 + r * 8;
        u16 v = 0;
        if (t < TPB) v = qkv[(size_t)(b * TPB + t) * 1536 + 1280 + g * 64 + d0 + tx];
        tile[ty0 + r * 8][tx] = v;
    }
    __syncthreads();
    #pragma unroll
    for (int r = 0; r < 4; r++) {
        int d = d0 + ty0 + r * 8;
        vt[((size_t)bg * 64 + d) * VTS + t0 + tx] = tile[tx][ty0 + r * 8];
    }
}

// ---------- RMSNorm(x) + prepend RAW gw tokens (16) -> h fp16 [4128][1024] ----------
__global__ __launch_bounds__(256) void rms_in_kernel(const float* __restrict__ x,
                                                     const float* __restrict__ w,
                                                     const float* __restrict__ gwp,
                                                     u16* __restrict__ h) {
    const int r = blockIdx.x;                 // 0..4127
    const int b = r / TPB, pos = r - b * TPB;
    const int tid = threadIdx.x;
    u16* hr = h + (size_t)r * 1024;
    if (pos < 16) {                           // raw gw tokens (not normalized)
        const float* s = gwp + (size_t)pos * 1024;
        for (int c = tid; c < 1024; c += 256) hr[c] = f2h(s[c]);
        return;
    }
    const float* xr = x + ((size_t)b * 2048 + (pos - 16)) * 1024;
    float v[4]; float ss = 0.f;
    #pragma unroll
    for (int i = 0; i < 4; i++) { v[i] = xr[tid + 256 * i]; ss += v[i] * v[i]; }
    ss = wave_sum(ss);
    __shared__ float red[4];
    if ((tid & 63) == 0) red[tid >> 6] = ss;
    __syncthreads();
    float tot = red[0] + red[1] + red[2] + red[3];
    float rn = rsqrtf(tot * (1.f / 1024.f) + 1e-6f);
    #pragma unroll
    for (int i = 0; i < 4; i++) hr[tid + 256 * i] = f2h(v[i] * rn * w[tid + 256 * i]);
}

// ---------- RMSNorm(y f32 [4096][1024]) -> z fp16 ----------
__global__ __launch_bounds__(256) void rms_row_kernel(const float* __restrict__ in,
                                                      const float* __restrict__ w,
                                                      u16* __restrict__ out) {
    const int r = blockIdx.x;
    const int tid = threadIdx.x;
    const float* xr = in + (size_t)r * 1024;
    float v[4]; float ss = 0.f;
    #pragma unroll
    for (int i = 0; i < 4; i++) { v[i] = xr[tid + 256 * i]; ss += v[i] * v[i]; }
    ss = wave_sum(ss);
    __shared__ float red[4];
    if ((tid & 63) == 0) red[tid >> 6] = ss;
    __syncthreads();
    float tot = red[0] + red[1] + red[2] + red[3];
    float rn = rsqrtf(tot * (1.f / 1024.f) + 1e-6f);
    u16* orow = out + (size_t)r * 1024;
    #pragma unroll
    for (int i = 0; i < 4; i++) orow[tid + 256 * i] = f2h(v[i] * rn * w[tid + 256 * i]);
}

// ---------- GEMM C = A * Bt^T (fp16, m97 structure) + XCD-aware block swizzle ----------
// EPI 0: fp16 C. EPI 1: f32 out = C + aux(f32). EPI 3: packed W1|W3 -> fp16 silu(c1)*c3,
//   output [M][N/2] (ldc = N/2). swzmode: 0 = row-chunk (A large), 1 = col-chunk (B large).
__device__ __forceinline__ void stage_tile(const u16* __restrict__ A, const u16* __restrict__ B,
                                           u16* As, u16* Bs, int m0, int n0, int k0,
                                           int M, int K, int tid) {
    const int wb = tid & ~63;
    #pragma unroll
    for (int t = 0; t < 2; t++) {
        int seg = t * 256 + tid;
        int row = seg >> 2, kc = seg & 3;
        int ar = m0 + row; if (ar > M - 1) ar = M - 1;
        gl_lds16(A + (size_t)ar * K + k0 + kc * 8, As + (size_t)(t * 256 + wb) * 8);
        gl_lds16(B + (size_t)(n0 + row) * K + k0 + kc * 8, Bs + (size_t)(t * 256 + wb) * 8);
    }
}

template <int EPI>
__global__ __launch_bounds__(256, 2) void gemm_bt(const u16* __restrict__ A,
                                                  const u16* __restrict__ B,
                                                  void* Cout,
                                                  const void* aux,
                                                  int M, int N, int K, int swzmode) {
    __shared__ __align__(16) u16 As[2][4096];
    __shared__ __align__(16) u16 Bs[2][4096];
    const int tid = threadIdx.x;
    // bijective XCD swizzle (m204): chunk the lid space into 8 contiguous runs
    const int gx = gridDim.x, gy = gridDim.y;
    const int nwg = gx * gy;
    int lid = swzmode ? (blockIdx.x * gy + blockIdx.y) : (blockIdx.y * gx + blockIdx.x);
    {
        const int q = nwg >> 3, rr = nwg & 7;
        const int xc = lid & 7, o = lid >> 3;
        lid = (xc < rr ? xc * (q + 1) : rr * (q + 1) + (xc - rr) * q) + o;
    }
    int bxs, bys;
    if (swzmode) { bxs = lid / gy; bys = lid - bxs * gy; }
    else         { bys = lid / gx; bxs = lid - bys * gx; }
    const int m0 = bys * 128, n0 = bxs * 128;

    const int w = tid >> 6, l = tid & 63;
    const int wr = w >> 1, wc = w & 1, lr = l & 15, lg = l >> 4;
    f32x4 acc[4][4] = {};
    const int NT = K >> 5;
    stage_tile(A, B, As[0], Bs[0], m0, n0, 0, M, K, tid);
    for (int t = 0; t < NT; t++) {
        const int p = t & 1;
        __syncthreads();                       // drains vmcnt(0): staged tile ready
        if (t + 1 < NT) stage_tile(A, B, As[p ^ 1], Bs[p ^ 1], m0, n0, (t + 1) * 32, M, K, tid);
        f16x8 af[4], bf[4];
        #pragma unroll
        for (int i = 0; i < 4; i++) {
            af[i] = *(const f16x8*)&As[p][(wr * 64 + i * 16 + lr) * 32 + lg * 8];
            bf[i] = *(const f16x8*)&Bs[p][(wc * 64 + i * 16 + lr) * 32 + lg * 8];
        }
        #pragma unroll
        for (int i = 0; i < 4; i++)
            #pragma unroll
            for (int j = 0; j < 4; j++)
                acc[i][j] = __builtin_amdgcn_mfma_f32_16x16x32_f16(af[i], bf[j], acc[i][j], 0, 0, 0);
    }
    if constexpr (EPI == 3) {
        // fused SwiGLU epilogue: j pairs (0,1)=(W1,W3) cols ucol0, (2,3) -> ucol0+16
        const int ldc = N >> 1;
        const int ucol0 = ((n0 + wc * 64) >> 1) + lr;
        #pragma unroll
        for (int i = 0; i < 4; i++) {
            const int rowb = m0 + wr * 64 + i * 16 + lg * 4;
            #pragma unroll
            for (int e = 0; e < 4; e++) {
                const int r2 = rowb + e;
                const float a0 = acc[i][0][e], a1 = acc[i][1][e];
                const float b0 = acc[i][2][e], b1 = acc[i][3][e];
                ((u16*)Cout)[(size_t)r2 * ldc + ucol0] = f2h(a0 / (1.f + __expf(-a0)) * a1);
                ((u16*)Cout)[(size_t)r2 * ldc + ucol0 + 16] = f2h(b0 / (1.f + __expf(-b0)) * b1);
            }
        }
    } else {
        #pragma unroll
        for (int i = 0; i < 4; i++) {
            const int rowb = m0 + wr * 64 + i * 16 + lg * 4;
            #pragma unroll
            for (int j = 0; j < 4; j++) {
                const int col = n0 + wc * 64 + j * 16 + lr;
                #pragma unroll
                for (int e = 0; e < 4; e++) {
                    const int r2 = rowb + e;
                    if (r2 < M) {
                        const size_t idx = (size_t)r2 * N + col;
                        const float v = acc[i][j][e];
                        if constexpr (EPI == 0) {
                            ((u16*)Cout)[idx] = f2h(v);
                        } else {
                            ((float*)Cout)[idx] = v + ((const float*)aux)[idx];
                        }
                    }
                }
            }
        }
    }
}

// ---------- flash attention: block = (fold-qt, g, b); 4 waves = 4 heads of group g ----------
__global__ __launch_bounds__(256) void attn_kernel(const u16* __restrict__ qkv,
                                                   const u16* __restrict__ vt,
                                                   u16* __restrict__ ctxn,
                                                   const float* __restrict__ hnw) {
    __shared__ __align__(16) u16 Ks[2][2048];
    __shared__ __align__(16) u16 Vs[2][2048];
    const int bx = blockIdx.x, g = blockIdx.y, b = blockIdx.z;
    const int tid = threadIdx.x;
    const int w = tid >> 6, l = tid & 63;
    const int lr = l & 15, lg = l >> 4;
    const int h = g * 4 + w;
    const int sig = 8 * (lr >> 2) + (lr & 3);
    const int LASTROW = TPB - 1;
    const u16* vtb = vt + (size_t)(b * 4 + g) * 64 * VTS;
    const u16* kbase = qkv + (size_t)b * TPB * 1536 + 1024 + g * 64;

    const int krow = tid >> 3;
    const int ksrc = (tid & 7) ^ ((krow & 3) | (((krow >> 3) & 1) << 2));
    const int vdv = tid >> 2;
    const int vsrc = (tid & 3) ^ ((vdv >> 1) & 3);
    const int wb8 = (tid & ~63) * 8;

    const int swzr = (sig & 3) | (((sig >> 3) & 1) << 2);
    const int ka0  = sig * 64 + ((lg ^ swzr) << 3);
    const int ka0b = sig * 64 + (((lg + 4) ^ swzr) << 3);
    const int ka1  = (sig + 4) * 64 + ((lg ^ swzr) << 3);
    const int ka1b = (sig + 4) * 64 + (((lg + 4) ^ swzr) << 3);
    int kv_off[4];
    #pragma unroll
    for (int dt = 0; dt < 4; dt++) {
        const int dv = dt * 16 + lr;
        kv_off[dt] = dv * 32 + ((lg ^ ((dv >> 1) & 3)) << 3);
    }

    const float hw0 = hnw[h * 64 + 0 * 16 + lr];
    const float hw1 = hnw[h * 64 + 1 * 16 + lr];
    const float hw2 = hnw[h * 64 + 2 * 16 + lr];
    const float hw3 = hnw[h * 64 + 3 * 16 + lr];

    for (int half = 0; half < 2; half++) {
        const int qt = half ? (127 - bx) : bx;
        const int orow0 = qt * 16;
        const int qpos0 = 16 + orow0;
        const int qpos = qpos0 + lr;
        const u16* qbase = qkv + (size_t)(b * TPB + qpos) * 1536 + h * 64;
        const f16x8 qf0 = *(const f16x8*)(qbase + lg * 8);
        const f16x8 qf1 = *(const f16x8*)(qbase + 32 + lg * 8);

        float m = -INFINITY, lsum = 0.f;
        f32x4 oc[4] = {};
        const int NT = ((qpos0 + 15) >> 5) + 1;

        __syncthreads();
        gl_lds16(kbase + (size_t)krow * 1536 + ksrc * 8, Ks[0] + wb8);
        gl_lds16(vtb + (size_t)vdv * VTS + vsrc * 8, Vs[0] + wb8);

        for (int kt = 0; kt < NT; kt++) {
            const int p = kt & 1;
            const int kb = kt * 32;
            __syncthreads();
            if (kt + 1 < NT) {
                const int kb2 = kb + 32;
                int kr = kb2 + krow; if (kr > LASTROW) kr = LASTROW;
                gl_lds16(kbase + (size_t)kr * 1536 + ksrc * 8, Ks[p ^ 1] + wb8);
                gl_lds16(vtb + (size_t)vdv * VTS + kb2 + vsrc * 8, Vs[p ^ 1] + wb8);
            }
            const f16x8 a0  = *(const f16x8*)&Ks[p][ka0];
            const f16x8 a0b = *(const f16x8*)&Ks[p][ka0b];
            const f16x8 a1  = *(const f16x8*)&Ks[p][ka1];
            const f16x8 a1b = *(const f16x8*)&Ks[p][ka1b];
            f16x8 vf[4];
            #pragma unroll
            for (int dt = 0; dt < 4; dt++) vf[dt] = *(const f16x8*)&Vs[p][kv_off[dt]];

            f32x4 st0 = {}, st1 = {};
            st0 = __builtin_amdgcn_mfma_f32_16x16x32_f16(a0,  qf0, st0, 0, 0, 0);
            st0 = __builtin_amdgcn_mfma_f32_16x16x32_f16(a0b, qf1, st0, 0, 0, 0);
            st1 = __builtin_amdgcn_mfma_f32_16x16x32_f16(a1,  qf0, st1, 0, 0, 0);
            st1 = __builtin_amdgcn_mfma_f32_16x16x32_f16(a1b, qf1, st1, 0, 0, 0);

            float sv[8]; float bm = -INFINITY;
            if (kb + 31 <= qpos0) {
                #pragma unroll
                for (int j = 0; j < 4; j++) {
                    sv[j] = st0[j] * 0.125f;
                    sv[4 + j] = st1[j] * 0.125f;
                    bm = fmaxf(bm, fmaxf(sv[j], sv[4 + j]));
                }
            } else {
                #pragma unroll
                for (int j = 0; j < 4; j++) {
                    const int kva = kb + 8 * lg + j;
                    float s0 = st0[j] * 0.125f; if (kva > qpos) s0 = -INFINITY;
                    float s1 = st1[j] * 0.125f; if (kva + 4 > qpos) s1 = -INFINITY;
                    sv[j] = s0; sv[4 + j] = s1;
                    bm = fmaxf(bm, fmaxf(s0, s1));
                }
            }
            bm = fmaxf(bm, __shfl_xor(bm, 16, 64));
            bm = fmaxf(bm, __shfl_xor(bm, 32, 64));
            if (!__all(bm - m <= 8.f)) {
                const float nm = fmaxf(m, bm);
                const float sc = __expf(m - nm);
                m = nm;
                lsum *= sc;
                float scj[4];
                #pragma unroll
                for (int j = 0; j < 4; j++) scj[j] = __shfl(sc, 4 * lg + j, 64);
                #pragma unroll
                for (int dt = 0; dt < 4; dt++)
                    #pragma unroll
                    for (int j = 0; j < 4; j++) oc[dt][j] *= scj[j];
            }
            float ps = 0.f;
            f16x8 pa;
            #pragma unroll
            for (int j = 0; j < 8; j++) {
                float p2 = __expf(sv[j] - m);
                ps += p2;
                pa[j] = (_Float16)p2;
            }
            ps += __shfl_xor(ps, 16, 64); ps += __shfl_xor(ps, 32, 64);
            lsum += ps;
            #pragma unroll
            for (int dt = 0; dt < 4; dt++)
                oc[dt] = __builtin_amdgcn_mfma_f32_16x16x32_f16(pa, vf[dt], oc[dt], 0, 0, 0);
        }
        float lj[4];
        #pragma unroll
        for (int j = 0; j < 4; j++) lj[j] = __shfl(lsum, 4 * lg + j, 64);
        float o[4][4]; float ssq[4] = {0, 0, 0, 0};
        #pragma unroll
        for (int dt = 0; dt < 4; dt++)
            #pragma unroll
            for (int j = 0; j < 4; j++) {
                float v = oc[dt][j] / lj[j];
                o[dt][j] = v; ssq[j] += v * v;
            }
        float rj[4];
        #pragma unroll
        for (int j = 0; j < 4; j++) {
            float s = ssq[j];
            s += __shfl_xor(s, 1, 64); s += __shfl_xor(s, 2, 64);
            s += __shfl_xor(s, 4, 64); s += __shfl_xor(s, 8, 64);
            rj[j] = rsqrtf(s * (1.f / 64.f) + 1e-6f);
        }
        const float hwv[4] = {hw0, hw1, hw2, hw3};
        #pragma unroll
        for (int dt = 0; dt < 4; dt++) {
            #pragma unroll
            for (int j = 0; j < 4; j++) {
                const int orow = orow0 + 4 * lg + j;
                ctxn[(size_t)(b * 2048 + orow) * 1024 + h * 64 + dt * 16 + lr] =
                    f2h(o[dt][j] * rj[j] * hwv[dt]);
            }
        }
    }
}

extern "C" void kernel_launch(void* const* d_in, const int* in_sizes, int n_in,
                              void* d_out, int out_size, void* d_ws, size_t ws_size,
                              hipStream_t stream) {
    const float* x   = (const float*)d_in[0];
    const float* wn  = (const float*)d_in[1];
    const float* gw  = (const float*)d_in[2];
    const float* Wq  = (const float*)d_in[3];
    const float* Wk  = (const float*)d_in[4];
    const float* Wv  = (const float*)d_in[5];
    const float* Wo  = (const float*)d_in[6];
    const float* hnw = (const float*)d_in[7];
    const float* wf  = (const float*)d_in[8];
    const float* W1  = (const float*)d_in[9];
    const float* W3  = (const float*)d_in[10];
    const float* W2  = (const float*)d_in[11];

    char* ws = (char*)d_ws;
    u16*  wqkv = (u16*)(ws + 0);           // [1536][1024] fp16
    u16*  wo_t = (u16*)(ws + 3145728);     // [1024][1024]
    u16*  w13t = (u16*)(ws + 5242880);     // [8192][1024] packed W1|W3 (16,777,216 B)
    u16*  w2t  = (u16*)(ws + 22020096);    // [1024][4096]
    u16*  hbuf = (u16*)(ws + 30408704);    // [4128][1024] fp16
    u16*  qkvb = (u16*)(ws + 38862848);    // [4128][1536] fp16
    u16*  ctxn = hbuf;                     // [4096][1024] overlays hbuf (dead after QKV)
    float* yb  = (float*)(ws + 51544064);  // [4096][1024] f32
    u16*  zb   = (u16*)(ws + 68321280);    // [4096][1024] fp16
    u16*  g1   = (u16*)(ws + 76709888);    // [4096][4096] fp16 (u buffer)
    u16*  vt   = (u16*)(ws + 110264320);   // [8][64][2080] fp16 -> end 112,394,240
    float* outp = (float*)d_out;

    const dim3 blk(256);
    wconv_t_kernel<<<dim3(32, 32), blk, 0, stream>>>(Wq, wqkv, 1024, 1024);
    wconv_t_kernel<<<dim3(8, 32), blk, 0, stream>>>(Wk, wqkv + 1024 * 1024, 1024, 256);
    wconv_t_kernel<<<dim3(8, 32), blk, 0, stream>>>(Wv, wqkv + 1280 * 1024, 1024, 256);
    wconv_t_kernel<<<dim3(32, 32), blk, 0, stream>>>(Wo, wo_t, 1024, 1024);
    wconv_pack13_kernel<<<dim3(128, 32), blk, 0, stream>>>(W1, W3, w13t);
    wconv_t_kernel<<<dim3(32, 128), blk, 0, stream>>>(W2, w2t, 4096, 1024);

    rms_in_kernel<<<dim3(NROW), blk, 0, stream>>>(x, wn, gw, hbuf);
    gemm_bt<0><<<dim3(12, 33), blk, 0, stream>>>(hbuf, wqkv, qkvb, nullptr, NROW, 1536, 1024, 0);
    vtrans_kernel<<<dim3(65, 2, 8), blk, 0, stream>>>(qkvb, vt);
    attn_kernel<<<dim3(64, 4, 2), blk, 0, stream>>>(qkvb, vt, ctxn, hnw);
    gemm_bt<1><<<dim3(8, 32), blk, 0, stream>>>(ctxn, wo_t, yb, x, 4096, 1024, 1024, 0);
    rms_row_kernel<<<dim3(4096), blk, 0, stream>>>(yb, wf, zb);
    gemm_bt<3><<<dim3(64, 32), blk, 0, stream>>>(zb, w13t, g1, nullptr, 4096, 8192, 1024, 1);
    gemm_bt<1><<<dim3(8, 32), blk, 0, stream>>>(g1, w2t, outp, yb, 4096, 1024, 4096, 0);
}

// Round 16
// 341.953 us; speedup vs baseline: 1.4385x; 1.0110x over previous
//
#include <hip/hip_runtime.h>

typedef unsigned short u16;
typedef __attribute__((ext_vector_type(8))) _Float16 f16x8;
typedef __attribute__((ext_vector_type(4))) float f32x4;

// GW=16 gw tokens; per-batch seq t = 2048+16 = 2064; total rows 2*2064 = 4128.
#define TPB 2064
#define NROW 4128
#define VTS 2080   // vt padded t-stride (zero tail)

__device__ __forceinline__ u16 f2h(float f) {
    _Float16 h = (_Float16)f;
    return __builtin_bit_cast(u16, h);
}
__device__ __forceinline__ float h2f(u16 u) {
    return (float)__builtin_bit_cast(_Float16, u);
}
__device__ __forceinline__ float wave_sum(float v) {
    #pragma unroll
    for (int m = 32; m; m >>= 1) v += __shfl_xor(v, m, 64);
    return v;
}
__device__ __forceinline__ void gl_lds16(const u16* g, u16* l) {
    __builtin_amdgcn_global_load_lds((const __attribute__((address_space(1))) void*)g,
                                     (__attribute__((address_space(3))) void*)l, 16, 0, 0);
}

// ---------- weight transpose-convert: f32 [K][N] -> fp16 [N][K] ----------
__global__ __launch_bounds__(256) void wconv_t_kernel(const float* __restrict__ src,
                                                      u16* __restrict__ dst, int K, int N) {
    __shared__ float tile[32][33];
    const int k0 = blockIdx.y * 32, n0 = blockIdx.x * 32;
    const int tx = threadIdx.x & 31, ty0 = threadIdx.x >> 5;
    #pragma unroll
    for (int r = 0; r < 4; r++) {
        int ky = ty0 + r * 8;
        tile[ky][tx] = src[(size_t)(k0 + ky) * N + n0 + tx];
    }
    __syncthreads();
    #pragma unroll
    for (int r = 0; r < 4; r++) {
        int ny = ty0 + r * 8;
        dst[(size_t)(n0 + ny) * K + k0 + tx] = f2h(tile[tx][ny]);
    }
}

// ---------- packed W1|W3 convert: f32 [1024][4096] x2 -> fp16 w13t [8192][1024] ----------
// Packed row p: group=p>>5 (16 u-cols), w=(p>>4)&1 (0=W1,1=W3), i=p&15; feature f=group*16+i.
__global__ __launch_bounds__(256) void wconv_pack13_kernel(const float* __restrict__ W1,
                                                           const float* __restrict__ W3,
                                                           u16* __restrict__ dst) {
    __shared__ float t1[32][33];
    __shared__ float t3[32][33];
    const int f0 = blockIdx.x * 32, k0 = blockIdx.y * 32;
    const int tx = threadIdx.x & 31, ty0 = threadIdx.x >> 5;
    #pragma unroll
    for (int r = 0; r < 4; r++) {
        int ky = ty0 + r * 8;
        t1[ky][tx] = W1[(size_t)(k0 + ky) * 4096 + f0 + tx];
        t3[ky][tx] = W3[(size_t)(k0 + ky) * 4096 + f0 + tx];
    }
    __syncthreads();
    #pragma unroll
    for (int r = 0; r < 4; r++) {
        int fy = ty0 + r * 8;
        int f = f0 + fy;
        int p1 = (f >> 4) * 32 + (f & 15);
        dst[(size_t)p1 * 1024 + k0 + tx] = f2h(t1[tx][fy]);
        dst[(size_t)(p1 + 16) * 1024 + k0 + tx] = f2h(t3[tx][fy]);
    }
}

// ---------- V transpose: qkv V-cols -> vt[b*4+g][dv=64][VTS] fp16 (zero tail) ----------
__global__ __launch_bounds__(256) void vtrans_kernel(const u16* __restrict__ qkv,
                                                     u16* __restrict__ vt) {
    __shared__ u16 tile[32][33];
    const int bg = blockIdx.z;                 // b*4+g
    const int b = bg >> 2, g = bg & 3;
    const int t0 = blockIdx.x * 32, d0 = blockIdx.y * 32;
    const int tx = threadIdx.x & 31, ty0 = threadIdx.x >> 5;
    #pragma unroll
    for (int r = 0; r < 4; r++) {
        int t = t0 + ty0 + r * 8;
        u16 v = 0;
        if (t < TPB) v = qkv[(size_t)(b * TPB + t) * 1536 + 1280 + g * 64 + d0 + tx];
        tile[ty0 + r * 8][tx] = v;
    }
    __syncthreads();
    #pragma unroll
    for (int r = 0; r < 4; r++) {
        int d = d0 + ty0 + r * 8;
        vt[((size_t)bg * 64 + d) * VTS + t0 + tx] = tile[tx][ty0 + r * 8];
    }
}

// ---------- RMSNorm(x) + prepend RAW gw tokens (16) -> h fp16 [4128][1024] ----------
__global__ __launch_bounds__(256) void rms_in_kernel(const float* __restrict__ x,
                                                     const float* __restrict__ w,
                                                     const float* __restrict__ gwp,
                                                     u16* __restrict__ h) {
    const int r = blockIdx.x;                 // 0..4127
    const int b = r / TPB, pos = r - b * TPB;
    const int tid = threadIdx.x;
    u16* hr = h + (size_t)r * 1024;
    if (pos < 16) {                           // raw gw tokens (not normalized)
        const float* s = gwp + (size_t)pos * 1024;
        for (int c = tid; c < 1024; c += 256) hr[c] = f2h(s[c]);
        return;
    }
    const float* xr = x + ((size_t)b * 2048 + (pos - 16)) * 1024;
    float v[4]; float ss = 0.f;
    #pragma unroll
    for (int i = 0; i < 4; i++) { v[i] = xr[tid + 256 * i]; ss += v[i] * v[i]; }
    ss = wave_sum(ss);
    __shared__ float red[4];
    if ((tid & 63) == 0) red[tid >> 6] = ss;
    __syncthreads();
    float tot = red[0] + red[1] + red[2] + red[3];
    float rn = rsqrtf(tot * (1.f / 1024.f) + 1e-6f);
    #pragma unroll
    for (int i = 0; i < 4; i++) hr[tid + 256 * i] = f2h(v[i] * rn * w[tid + 256 * i]);
}

// ---------- RMSNorm(y f32 [4096][1024]) -> z fp16 ----------
__global__ __launch_bounds__(256) void rms_row_kernel(const float* __restrict__ in,
                                                      const float* __restrict__ w,
                                                      u16* __restrict__ out) {
    const int r = blockIdx.x;
    const int tid = threadIdx.x;
    const float* xr = in + (size_t)r * 1024;
    float v[4]; float ss = 0.f;
    #pragma unroll
    for (int i = 0; i < 4; i++) { v[i] = xr[tid + 256 * i]; ss += v[i] * v[i]; }
    ss = wave_sum(ss);
    __shared__ float red[4];
    if ((tid & 63) == 0) red[tid >> 6] = ss;
    __syncthreads();
    float tot = red[0] + red[1] + red[2] + red[3];
    float rn = rsqrtf(tot * (1.f / 1024.f) + 1e-6f);
    u16* orow = out + (size_t)r * 1024;
    #pragma unroll
    for (int i = 0; i < 4; i++) orow[tid + 256 * i] = f2h(v[i] * rn * w[tid + 256 * i]);
}

// ---------- GEMM C = A * Bt^T (fp16, m97 structure) + XCD-aware block swizzle ----------
// EPI 0: fp16 C. EPI 1: f32 out = C + aux(f32). EPI 3: packed W1|W3 -> fp16 silu(c1)*c3,
//   output [M][N/2] (ldc = N/2).
// swzmode: 0 = row-chunk (A large), 1 = col-chunk (B large),
//          2 = col-chunk + 8x(gx/8) supertiles (needs gx%8==0, gy%8==0): per-XCD
//              concurrent set = 8 A-panels + 8 B-panels ~ 4 MB = L2-resident.
__device__ __forceinline__ void stage_tile(const u16* __restrict__ A, const u16* __restrict__ B,
                                           u16* As, u16* Bs, int m0, int n0, int k0,
                                           int M, int K, int tid) {
    const int wb = tid & ~63;
    #pragma unroll
    for (int t = 0; t < 2; t++) {
        int seg = t * 256 + tid;
        int row = seg >> 2, kc = seg & 3;
        int ar = m0 + row; if (ar > M - 1) ar = M - 1;
        gl_lds16(A + (size_t)ar * K + k0 + kc * 8, As + (size_t)(t * 256 + wb) * 8);
        gl_lds16(B + (size_t)(n0 + row) * K + k0 + kc * 8, Bs + (size_t)(t * 256 + wb) * 8);
    }
}

template <int EPI>
__global__ __launch_bounds__(256, 2) void gemm_bt(const u16* __restrict__ A,
                                                  const u16* __restrict__ B,
                                                  void* Cout,
                                                  const void* aux,
                                                  int M, int N, int K, int swzmode) {
    __shared__ __align__(16) u16 As[2][4096];
    __shared__ __align__(16) u16 Bs[2][4096];
    const int tid = threadIdx.x;
    const int gx = gridDim.x, gy = gridDim.y;
    int bxs, bys;
    if (swzmode == 2) {
        // 2-level: XCD chunk (cols) -> 8-row supertiles, n fastest within supertile
        const int bid = blockIdx.y * gx + blockIdx.x;
        const int xc = bid & 7, cid = bid >> 3;
        const int cx = gx >> 3;                  // n-cols per XCD
        const int stb = cid / (cx << 3);         // supertile (8 m-rows x cx n-cols)
        const int rem = cid - stb * (cx << 3);
        const int sm = rem / cx, sn = rem - sm * cx;
        bys = stb * 8 + sm;
        bxs = xc * cx + sn;
    } else {
        const int nwg = gx * gy;
        int lid = swzmode ? (blockIdx.x * gy + blockIdx.y) : (blockIdx.y * gx + blockIdx.x);
        const int q = nwg >> 3, rr = nwg & 7;
        const int xc = lid & 7, o = lid >> 3;
        lid = (xc < rr ? xc * (q + 1) : rr * (q + 1) + (xc - rr) * q) + o;
        if (swzmode) { bxs = lid / gy; bys = lid - bxs * gy; }
        else         { bys = lid / gx; bxs = lid - bys * gx; }
    }
    const int m0 = bys * 128, n0 = bxs * 128;

    const int w = tid >> 6, l = tid & 63;
    const int wr = w >> 1, wc = w & 1, lr = l & 15, lg = l >> 4;
    f32x4 acc[4][4] = {};
    const int NT = K >> 5;
    stage_tile(A, B, As[0], Bs[0], m0, n0, 0, M, K, tid);
    for (int t = 0; t < NT; t++) {
        const int p = t & 1;
        __syncthreads();                       // drains vmcnt(0): staged tile ready
        if (t + 1 < NT) stage_tile(A, B, As[p ^ 1], Bs[p ^ 1], m0, n0, (t + 1) * 32, M, K, tid);
        f16x8 af[4], bf[4];
        #pragma unroll
        for (int i = 0; i < 4; i++) {
            af[i] = *(const f16x8*)&As[p][(wr * 64 + i * 16 + lr) * 32 + lg * 8];
            bf[i] = *(const f16x8*)&Bs[p][(wc * 64 + i * 16 + lr) * 32 + lg * 8];
        }
        #pragma unroll
        for (int i = 0; i < 4; i++)
            #pragma unroll
            for (int j = 0; j < 4; j++)
                acc[i][j] = __builtin_amdgcn_mfma_f32_16x16x32_f16(af[i], bf[j], acc[i][j], 0, 0, 0);
    }
    if constexpr (EPI == 3) {
        // fused SwiGLU epilogue: j pairs (0,1)=(W1,W3) cols ucol0, (2,3) -> ucol0+16
        const int ldc = N >> 1;
        const int ucol0 = ((n0 + wc * 64) >> 1) + lr;
        #pragma unroll
        for (int i = 0; i < 4; i++) {
            const int rowb = m0 + wr * 64 + i * 16 + lg * 4;
            #pragma unroll
            for (int e = 0; e < 4; e++) {
                const int r2 = rowb + e;
                const float a0 = acc[i][0][e], a1 = acc[i][1][e];
                const float b0 = acc[i][2][e], b1 = acc[i][3][e];
                ((u16*)Cout)[(size_t)r2 * ldc + ucol0] = f2h(a0 / (1.f + __expf(-a0)) * a1);
                ((u16*)Cout)[(size_t)r2 * ldc + ucol0 + 16] = f2h(b0 / (1.f + __expf(-b0)) * b1);
            }
        }
    } else {
        #pragma unroll
        for (int i = 0; i < 4; i++) {
            const int rowb = m0 + wr * 64 + i * 16 + lg * 4;
            #pragma unroll
            for (int j = 0; j < 4; j++) {
                const int col = n0 + wc * 64 + j * 16 + lr;
                #pragma unroll
                for (int e = 0; e < 4; e++) {
                    const int r2 = rowb + e;
                    if (r2 < M) {
                        const size_t idx = (size_t)r2 * N + col;
                        const float v = acc[i][j][e];
                        if constexpr (EPI == 0) {
                            ((u16*)Cout)[idx] = f2h(v);
                        } else {
                            ((float*)Cout)[idx] = v + ((const float*)aux)[idx];
                        }
                    }
                }
            }
        }
    }
}

// ---------- flash attention: block = (fold-qt, g, b); 4 waves = 4 heads of group g ----------
__global__ __launch_bounds__(256) void attn_kernel(const u16* __restrict__ qkv,
                                                   const u16* __restrict__ vt,
                                                   u16* __restrict__ ctxn,
                                                   const float* __restrict__ hnw) {
    __shared__ __align__(16) u16 Ks[2][2048];
    __shared__ __align__(16) u16 Vs[2][2048];
    const int bx = blockIdx.x, g = blockIdx.y, b = blockIdx.z;
    const int tid = threadIdx.x;
    const int w = tid >> 6, l = tid & 63;
    const int lr = l & 15, lg = l >> 4;
    const int h = g * 4 + w;
    const int sig = 8 * (lr >> 2) + (lr & 3);
    const int LASTROW = TPB - 1;
    const u16* vtb = vt + (size_t)(b * 4 + g) * 64 * VTS;
    const u16* kbase = qkv + (size_t)b * TPB * 1536 + 1024 + g * 64;

    const int krow = tid >> 3;
    const int ksrc = (tid & 7) ^ ((krow & 3) | (((krow >> 3) & 1) << 2));
    const int vdv = tid >> 2;
    const int vsrc = (tid & 3) ^ ((vdv >> 1) & 3);
    const int wb8 = (tid & ~63) * 8;

    const int swzr = (sig & 3) | (((sig >> 3) & 1) << 2);
    const int ka0  = sig * 64 + ((lg ^ swzr) << 3);
    const int ka0b = sig * 64 + (((lg + 4) ^ swzr) << 3);
    const int ka1  = (sig + 4) * 64 + ((lg ^ swzr) << 3);
    const int ka1b = (sig + 4) * 64 + (((lg + 4) ^ swzr) << 3);
    int kv_off[4];
    #pragma unroll
    for (int dt = 0; dt < 4; dt++) {
        const int dv = dt * 16 + lr;
        kv_off[dt] = dv * 32 + ((lg ^ ((dv >> 1) & 3)) << 3);
    }

    const float hw0 = hnw[h * 64 + 0 * 16 + lr];
    const float hw1 = hnw[h * 64 + 1 * 16 + lr];
    const float hw2 = hnw[h * 64 + 2 * 16 + lr];
    const float hw3 = hnw[h * 64 + 3 * 16 + lr];

    for (int half = 0; half < 2; half++) {
        const int qt = half ? (127 - bx) : bx;
        const int orow0 = qt * 16;
        const int qpos0 = 16 + orow0;
        const int qpos = qpos0 + lr;
        const u16* qbase = qkv + (size_t)(b * TPB + qpos) * 1536 + h * 64;
        const f16x8 qf0 = *(const f16x8*)(qbase + lg * 8);
        const f16x8 qf1 = *(const f16x8*)(qbase + 32 + lg * 8);

        float m = -INFINITY, lsum = 0.f;
        f32x4 oc[4] = {};
        const int NT = ((qpos0 + 15) >> 5) + 1;

        __syncthreads();
        gl_lds16(kbase + (size_t)krow * 1536 + ksrc * 8, Ks[0] + wb8);
        gl_lds16(vtb + (size_t)vdv * VTS + vsrc * 8, Vs[0] + wb8);

        for (int kt = 0; kt < NT; kt++) {
            const int p = kt & 1;
            const int kb = kt * 32;
            __syncthreads();
            if (kt + 1 < NT) {
                const int kb2 = kb + 32;
                int kr = kb2 + krow; if (kr > LASTROW) kr = LASTROW;
                gl_lds16(kbase + (size_t)kr * 1536 + ksrc * 8, Ks[p ^ 1] + wb8);
                gl_lds16(vtb + (size_t)vdv * VTS + kb2 + vsrc * 8, Vs[p ^ 1] + wb8);
            }
            const f16x8 a0  = *(const f16x8*)&Ks[p][ka0];
            const f16x8 a0b = *(const f16x8*)&Ks[p][ka0b];
            const f16x8 a1  = *(const f16x8*)&Ks[p][ka1];
            const f16x8 a1b = *(const f16x8*)&Ks[p][ka1b];
            f16x8 vf[4];
            #pragma unroll
            for (int dt = 0; dt < 4; dt++) vf[dt] = *(const f16x8*)&Vs[p][kv_off[dt]];

            f32x4 st0 = {}, st1 = {};
            st0 = __builtin_amdgcn_mfma_f32_16x16x32_f16(a0,  qf0, st0, 0, 0, 0);
            st0 = __builtin_amdgcn_mfma_f32_16x16x32_f16(a0b, qf1, st0, 0, 0, 0);
            st1 = __builtin_amdgcn_mfma_f32_16x16x32_f16(a1,  qf0, st1, 0, 0, 0);
            st1 = __builtin_amdgcn_mfma_f32_16x16x32_f16(a1b, qf1, st1, 0, 0, 0);

            float sv[8]; float bm = -INFINITY;
            if (kb + 31 <= qpos0) {
                #pragma unroll
                for (int j = 0; j < 4; j++) {
                    sv[j] = st0[j] * 0.125f;
                    sv[4 + j] = st1[j] * 0.125f;
                    bm = fmaxf(bm, fmaxf(sv[j], sv[4 + j]));
                }
            } else {
                #pragma unroll
                for (int j = 0; j < 4; j++) {
                    const int kva = kb + 8 * lg + j;
                    float s0 = st0[j] * 0.125f; if (kva > qpos) s0 = -INFINITY;
                    float s1 = st1[j] * 0.125f; if (kva + 4 > qpos) s1 = -INFINITY;
                    sv[j] = s0; sv[4 + j] = s1;
                    bm = fmaxf(bm, fmaxf(s0, s1));
                }
            }
            bm = fmaxf(bm, __shfl_xor(bm, 16, 64));
            bm = fmaxf(bm, __shfl_xor(bm, 32, 64));
            if (!__all(bm - m <= 8.f)) {
                const float nm = fmaxf(m, bm);
                const float sc = __expf(m - nm);
                m = nm;
                lsum *= sc;
                float scj[4];
                #pragma unroll
                for (int j = 0; j < 4; j++) scj[j] = __shfl(sc, 4 * lg + j, 64);
                #pragma unroll
                for (int dt = 0; dt < 4; dt++)
                    #pragma unroll
                    for (int j = 0; j < 4; j++) oc[dt][j] *= scj[j];
            }
            float ps = 0.f;
            f16x8 pa;
            #pragma unroll
            for (int j = 0; j < 8; j++) {
                float p2 = __expf(sv[j] - m);
                ps += p2;
                pa[j] = (_Float16)p2;
            }
            ps += __shfl_xor(ps, 16, 64); ps += __shfl_xor(ps, 32, 64);
            lsum += ps;
            #pragma unroll
            for (int dt = 0; dt < 4; dt++)
                oc[dt] = __builtin_amdgcn_mfma_f32_16x16x32_f16(pa, vf[dt], oc[dt], 0, 0, 0);
        }
        float lj[4];
        #pragma unroll
        for (int j = 0; j < 4; j++) lj[j] = __shfl(lsum, 4 * lg + j, 64);
        float o[4][4]; float ssq[4] = {0, 0, 0, 0};
        #pragma unroll
        for (int dt = 0; dt < 4; dt++)
            #pragma unroll
            for (int j = 0; j < 4; j++) {
                float v = oc[dt][j] / lj[j];
                o[dt][j] = v; ssq[j] += v * v;
            }
        float rj[4];
        #pragma unroll
        for (int j = 0; j < 4; j++) {
            float s = ssq[j];
            s += __shfl_xor(s, 1, 64); s += __shfl_xor(s, 2, 64);
            s += __shfl_xor(s, 4, 64); s += __shfl_xor(s, 8, 64);
            rj[j] = rsqrtf(s * (1.f / 64.f) + 1e-6f);
        }
        const float hwv[4] = {hw0, hw1, hw2, hw3};
        #pragma unroll
        for (int dt = 0; dt < 4; dt++) {
            #pragma unroll
            for (int j = 0; j < 4; j++) {
                const int orow = orow0 + 4 * lg + j;
                ctxn[(size_t)(b * 2048 + orow) * 1024 + h * 64 + dt * 16 + lr] =
                    f2h(o[dt][j] * rj[j] * hwv[dt]);
            }
        }
    }
}

extern "C" void kernel_launch(void* const* d_in, const int* in_sizes, int n_in,
                              void* d_out, int out_size, void* d_ws, size_t ws_size,
                              hipStream_t stream) {
    const float* x   = (const float*)d_in[0];
    const float* wn  = (const float*)d_in[1];
    const float* gw  = (const float*)d_in[2];
    const float* Wq  = (const float*)d_in[3];
    const float* Wk  = (const float*)d_in[4];
    const float* Wv  = (const float*)d_in[5];
    const float* Wo  = (const float*)d_in[6];
    const float* hnw = (const float*)d_in[7];
    const float* wf  = (const float*)d_in[8];
    const float* W1  = (const float*)d_in[9];
    const float* W3  = (const float*)d_in[10];
    const float* W2  = (const float*)d_in[11];

    char* ws = (char*)d_ws;
    u16*  wqkv = (u16*)(ws + 0);           // [1536][1024] fp16
    u16*  wo_t = (u16*)(ws + 3145728);     // [1024][1024]
    u16*  w13t = (u16*)(ws + 5242880);     // [8192][1024] packed W1|W3 (16,777,216 B)
    u16*  w2t  = (u16*)(ws + 22020096);    // [1024][4096]
    u16*  hbuf = (u16*)(ws + 30408704);    // [4128][1024] fp16
    u16*  qkvb = (u16*)(ws + 38862848);    // [4128][1536] fp16
    u16*  ctxn = hbuf;                     // [4096][1024] overlays hbuf (dead after QKV)
    float* yb  = (float*)(ws + 51544064);  // [4096][1024] f32
    u16*  zb   = (u16*)(ws + 68321280);    // [4096][1024] fp16
    u16*  g1   = (u16*)(ws + 76709888);    // [4096][4096] fp16 (u buffer)
    u16*  vt   = (u16*)(ws + 110264320);   // [8][64][2080] fp16 -> end 112,394,240
    float* outp = (float*)d_out;

    const dim3 blk(256);
    wconv_t_kernel<<<dim3(32, 32), blk, 0, stream>>>(Wq, wqkv, 1024, 1024);
    wconv_t_kernel<<<dim3(8, 32), blk, 0, stream>>>(Wk, wqkv + 1024 * 1024, 1024, 256);
    wconv_t_kernel<<<dim3(8, 32), blk, 0, stream>>>(Wv, wqkv + 1280 * 1024, 1024, 256);
    wconv_t_kernel<<<dim3(32, 32), blk, 0, stream>>>(Wo, wo_t, 1024, 1024);
    wconv_pack13_kernel<<<dim3(128, 32), blk, 0, stream>>>(W1, W3, w13t);
    wconv_t_kernel<<<dim3(32, 128), blk, 0, stream>>>(W2, w2t, 4096, 1024);

    rms_in_kernel<<<dim3(NROW), blk, 0, stream>>>(x, wn, gw, hbuf);
    gemm_bt<0><<<dim3(12, 33), blk, 0, stream>>>(hbuf, wqkv, qkvb, nullptr, NROW, 1536, 1024, 0);
    vtrans_kernel<<<dim3(65, 2, 8), blk, 0, stream>>>(qkvb, vt);
    attn_kernel<<<dim3(64, 4, 2), blk, 0, stream>>>(qkvb, vt, ctxn, hnw);
    gemm_bt<1><<<dim3(8, 32), blk, 0, stream>>>(ctxn, wo_t, yb, x, 4096, 1024, 1024, 0);
    rms_row_kernel<<<dim3(4096), blk, 0, stream>>>(yb, wf, zb);
    gemm_bt<3><<<dim3(64, 32), blk, 0, stream>>>(zb, w13t, g1, nullptr, 4096, 8192, 1024, 2);
    gemm_bt<1><<<dim3(8, 32), blk, 0, stream>>>(g1, w2t, outp, yb, 4096, 1024, 4096, 0);
}

// Round 17
// 322.062 us; speedup vs baseline: 1.5274x; 1.0618x over previous
//
#include <hip/hip_runtime.h>

typedef unsigned short u16;
typedef __attribute__((ext_vector_type(8))) _Float16 f16x8;
typedef __attribute__((ext_vector_type(4))) float f32x4;

// GW=16 gw tokens; per-batch seq t = 2048+16 = 2064; total rows 2*2064 = 4128.
#define TPB 2064
#define NROW 4128
#define VTS 2080   // vt padded t-stride (zero tail)

__device__ __forceinline__ u16 f2h(float f) {
    _Float16 h = (_Float16)f;
    return __builtin_bit_cast(u16, h);
}
__device__ __forceinline__ float h2f(u16 u) {
    return (float)__builtin_bit_cast(_Float16, u);
}
__device__ __forceinline__ float wave_sum(float v) {
    #pragma unroll
    for (int m = 32; m; m >>= 1) v += __shfl_xor(v, m, 64);
    return v;
}
__device__ __forceinline__ void gl_lds16(const u16* g, u16* l) {
    __builtin_amdgcn_global_load_lds((const __attribute__((address_space(1))) void*)g,
                                     (__attribute__((address_space(3))) void*)l, 16, 0, 0);
}

// ---------- weight transpose-convert: f32 [K][N] -> fp16 [N][K] ----------
__global__ __launch_bounds__(256) void wconv_t_kernel(const float* __restrict__ src,
                                                      u16* __restrict__ dst, int K, int N) {
    __shared__ float tile[32][33];
    const int k0 = blockIdx.y * 32, n0 = blockIdx.x * 32;
    const int tx = threadIdx.x & 31, ty0 = threadIdx.x >> 5;
    #pragma unroll
    for (int r = 0; r < 4; r++) {
        int ky = ty0 + r * 8;
        tile[ky][tx] = src[(size_t)(k0 + ky) * N + n0 + tx];
    }
    __syncthreads();
    #pragma unroll
    for (int r = 0; r < 4; r++) {
        int ny = ty0 + r * 8;
        dst[(size_t)(n0 + ny) * K + k0 + tx] = f2h(tile[tx][ny]);
    }
}

// ---------- packed W1|W3 convert: f32 [1024][4096] x2 -> fp16 w13t [8192][1024] ----------
__global__ __launch_bounds__(256) void wconv_pack13_kernel(const float* __restrict__ W1,
                                                           const float* __restrict__ W3,
                                                           u16* __restrict__ dst) {
    __shared__ float t1[32][33];
    __shared__ float t3[32][33];
    const int f0 = blockIdx.x * 32, k0 = blockIdx.y * 32;
    const int tx = threadIdx.x & 31, ty0 = threadIdx.x >> 5;
    #pragma unroll
    for (int r = 0; r < 4; r++) {
        int ky = ty0 + r * 8;
        t1[ky][tx] = W1[(size_t)(k0 + ky) * 4096 + f0 + tx];
        t3[ky][tx] = W3[(size_t)(k0 + ky) * 4096 + f0 + tx];
    }
    __syncthreads();
    #pragma unroll
    for (int r = 0; r < 4; r++) {
        int fy = ty0 + r * 8;
        int f = f0 + fy;
        int p1 = (f >> 4) * 32 + (f & 15);
        dst[(size_t)p1 * 1024 + k0 + tx] = f2h(t1[tx][fy]);
        dst[(size_t)(p1 + 16) * 1024 + k0 + tx] = f2h(t3[tx][fy]);
    }
}

// ---------- V transpose: qkv V-cols -> vt[b*4+g][dv=64][VTS] fp16 (zero tail) ----------
__global__ __launch_bounds__(256) void vtrans_kernel(const u16* __restrict__ qkv,
                                                     u16* __restrict__ vt) {
    __shared__ u16 tile[32][33];
    const int bg = blockIdx.z;                 // b*4+g
    const int b = bg >> 2, g = bg & 3;
    const int t0 = blockIdx.x * 32, d0 = blockIdx.y * 32;
    const int tx = threadIdx.x & 31, ty0 = threadIdx.x >> 5;
    #pragma unroll
    for (int r = 0; r < 4; r++) {
        int t = t0 + ty0 + r * 8;
        u16 v = 0;
        if (t < TPB) v = qkv[(size_t)(b * TPB + t) * 1536 + 1280 + g * 64 + d0 + tx];
        tile[ty0 + r * 8][tx] = v;
    }
    __syncthreads();
    #pragma unroll
    for (int r = 0; r < 4; r++) {
        int d = d0 + ty0 + r * 8;
        vt[((size_t)bg * 64 + d) * VTS + t0 + tx] = tile[tx][ty0 + r * 8];
    }
}

// ---------- RMSNorm(x) + prepend RAW gw tokens (16) -> h fp16 [4128][1024] ----------
__global__ __launch_bounds__(256) void rms_in_kernel(const float* __restrict__ x,
                                                     const float* __restrict__ w,
                                                     const float* __restrict__ gwp,
                                                     u16* __restrict__ h) {
    const int r = blockIdx.x;                 // 0..4127
    const int b = r / TPB, pos = r - b * TPB;
    const int tid = threadIdx.x;
    u16* hr = h + (size_t)r * 1024;
    if (pos < 16) {                           // raw gw tokens (not normalized)
        const float* s = gwp + (size_t)pos * 1024;
        for (int c = tid; c < 1024; c += 256) hr[c] = f2h(s[c]);
        return;
    }
    const float* xr = x + ((size_t)b * 2048 + (pos - 16)) * 1024;
    float v[4]; float ss = 0.f;
    #pragma unroll
    for (int i = 0; i < 4; i++) { v[i] = xr[tid + 256 * i]; ss += v[i] * v[i]; }
    ss = wave_sum(ss);
    __shared__ float red[4];
    if ((tid & 63) == 0) red[tid >> 6] = ss;
    __syncthreads();
    float tot = red[0] + red[1] + red[2] + red[3];
    float rn = rsqrtf(tot * (1.f / 1024.f) + 1e-6f);
    #pragma unroll
    for (int i = 0; i < 4; i++) hr[tid + 256 * i] = f2h(v[i] * rn * w[tid + 256 * i]);
}

// ---------- RMSNorm(y f32 [4096][1024]) -> z fp16 ----------
__global__ __launch_bounds__(256) void rms_row_kernel(const float* __restrict__ in,
                                                      const float* __restrict__ w,
                                                      u16* __restrict__ out) {
    const int r = blockIdx.x;
    const int tid = threadIdx.x;
    const float* xr = in + (size_t)r * 1024;
    float v[4]; float ss = 0.f;
    #pragma unroll
    for (int i = 0; i < 4; i++) { v[i] = xr[tid + 256 * i]; ss += v[i] * v[i]; }
    ss = wave_sum(ss);
    __shared__ float red[4];
    if ((tid & 63) == 0) red[tid >> 6] = ss;
    __syncthreads();
    float tot = red[0] + red[1] + red[2] + red[3];
    float rn = rsqrtf(tot * (1.f / 1024.f) + 1e-6f);
    u16* orow = out + (size_t)r * 1024;
    #pragma unroll
    for (int i = 0; i < 4; i++) orow[tid + 256 * i] = f2h(v[i] * rn * w[tid + 256 * i]);
}

// ---------- combine: out[i] += part[i]  (f32x4 vectorized, deterministic) ----------
__global__ __launch_bounds__(256) void combine_kernel(float* __restrict__ out,
                                                      const float* __restrict__ part) {
    const size_t i = ((size_t)blockIdx.x * 256 + threadIdx.x) * 4;
    f32x4 a = *(const f32x4*)&out[i];
    const f32x4 b = *(const f32x4*)&part[i];
    a[0] += b[0]; a[1] += b[1]; a[2] += b[2]; a[3] += b[3];
    *(f32x4*)&out[i] = a;
}

// ---------- GEMM C = A * Bt^T (fp16, m97 structure) + XCD-aware block swizzle ----------
// EPI 0: fp16 C. EPI 1: f32 out = C + aux(f32). EPI 3: packed W1|W3 -> fp16 silu(c1)*c3,
//   output [M][N/2]. EPI 4: split-K over blockIdx.z: z=0 raw f32 C -> Cout2;
//   z=1 f32 C + aux -> Cout. KL = K-length per z (k0base = z*KL); K = row stride.
// swzmode: 0 = row-chunk, 1 = col-chunk, 2 = col-chunk + 8-row supertiles.
__device__ __forceinline__ void stage_tile(const u16* __restrict__ A, const u16* __restrict__ B,
                                           u16* As, u16* Bs, int m0, int n0, int k0,
                                           int M, int K, int tid) {
    const int wb = tid & ~63;
    #pragma unroll
    for (int t = 0; t < 2; t++) {
        int seg = t * 256 + tid;
        int row = seg >> 2, kc = seg & 3;
        int ar = m0 + row; if (ar > M - 1) ar = M - 1;
        gl_lds16(A + (size_t)ar * K + k0 + kc * 8, As + (size_t)(t * 256 + wb) * 8);
        gl_lds16(B + (size_t)(n0 + row) * K + k0 + kc * 8, Bs + (size_t)(t * 256 + wb) * 8);
    }
}

template <int EPI>
__global__ __launch_bounds__(256, 2) void gemm_bt(const u16* __restrict__ A,
                                                  const u16* __restrict__ B,
                                                  void* Cout,
                                                  const void* aux,
                                                  int M, int N, int K, int swzmode,
                                                  int KL, void* Cout2) {
    __shared__ __align__(16) u16 As[2][4096];
    __shared__ __align__(16) u16 Bs[2][4096];
    const int tid = threadIdx.x;
    const int gx = gridDim.x, gy = gridDim.y;
    int bxs, bys;
    if (swzmode == 2) {
        const int bid = blockIdx.y * gx + blockIdx.x;
        const int xc = bid & 7, cid = bid >> 3;
        const int cx = gx >> 3;
        const int stb = cid / (cx << 3);
        const int rem = cid - stb * (cx << 3);
        const int sm = rem / cx, sn = rem - sm * cx;
        bys = stb * 8 + sm;
        bxs = xc * cx + sn;
    } else {
        const int nwg = gx * gy;
        int lid = swzmode ? (blockIdx.x * gy + blockIdx.y) : (blockIdx.y * gx + blockIdx.x);
        const int q = nwg >> 3, rr = nwg & 7;
        const int xc = lid & 7, o = lid >> 3;
        lid = (xc < rr ? xc * (q + 1) : rr * (q + 1) + (xc - rr) * q) + o;
        if (swzmode) { bxs = lid / gy; bys = lid - bxs * gy; }
        else         { bys = lid / gx; bxs = lid - bys * gx; }
    }
    const int m0 = bys * 128, n0 = bxs * 128;
    const int kbase = blockIdx.z * KL;

    const int w = tid >> 6, l = tid & 63;
    const int wr = w >> 1, wc = w & 1, lr = l & 15, lg = l >> 4;
    f32x4 acc[4][4] = {};
    const int NT = KL >> 5;
    stage_tile(A, B, As[0], Bs[0], m0, n0, kbase, M, K, tid);
    for (int t = 0; t < NT; t++) {
        const int p = t & 1;
        __syncthreads();                       // drains vmcnt(0): staged tile ready
        if (t + 1 < NT) stage_tile(A, B, As[p ^ 1], Bs[p ^ 1], m0, n0, kbase + (t + 1) * 32, M, K, tid);
        f16x8 af[4], bf[4];
        #pragma unroll
        for (int i = 0; i < 4; i++) {
            af[i] = *(const f16x8*)&As[p][(wr * 64 + i * 16 + lr) * 32 + lg * 8];
            bf[i] = *(const f16x8*)&Bs[p][(wc * 64 + i * 16 + lr) * 32 + lg * 8];
        }
        #pragma unroll
        for (int i = 0; i < 4; i++)
            #pragma unroll
            for (int j = 0; j < 4; j++)
                acc[i][j] = __builtin_amdgcn_mfma_f32_16x16x32_f16(af[i], bf[j], acc[i][j], 0, 0, 0);
    }
    if constexpr (EPI == 3) {
        const int ldc = N >> 1;
        const int ucol0 = ((n0 + wc * 64) >> 1) + lr;
        #pragma unroll
        for (int i = 0; i < 4; i++) {
            const int rowb = m0 + wr * 64 + i * 16 + lg * 4;
            #pragma unroll
            for (int e = 0; e < 4; e++) {
                const int r2 = rowb + e;
                const float a0 = acc[i][0][e], a1 = acc[i][1][e];
                const float b0 = acc[i][2][e], b1 = acc[i][3][e];
                ((u16*)Cout)[(size_t)r2 * ldc + ucol0] = f2h(a0 / (1.f + __expf(-a0)) * a1);
                ((u16*)Cout)[(size_t)r2 * ldc + ucol0 + 16] = f2h(b0 / (1.f + __expf(-b0)) * b1);
            }
        }
    } else if constexpr (EPI == 4) {
        float* dst0 = (float*)Cout2;
        float* dst1 = (float*)Cout;
        const bool z0 = (blockIdx.z == 0);
        #pragma unroll
        for (int i = 0; i < 4; i++) {
            const int rowb = m0 + wr * 64 + i * 16 + lg * 4;
            #pragma unroll
            for (int j = 0; j < 4; j++) {
                const int col = n0 + wc * 64 + j * 16 + lr;
                #pragma unroll
                for (int e = 0; e < 4; e++) {
                    const int r2 = rowb + e;
                    const size_t idx = (size_t)r2 * N + col;
                    const float v = acc[i][j][e];
                    if (z0) dst0[idx] = v;
                    else    dst1[idx] = v + ((const float*)aux)[idx];
                }
            }
        }
    } else {
        #pragma unroll
        for (int i = 0; i < 4; i++) {
            const int rowb = m0 + wr * 64 + i * 16 + lg * 4;
            #pragma unroll
            for (int j = 0; j < 4; j++) {
                const int col = n0 + wc * 64 + j * 16 + lr;
                #pragma unroll
                for (int e = 0; e < 4; e++) {
                    const int r2 = rowb + e;
                    if (r2 < M) {
                        const size_t idx = (size_t)r2 * N + col;
                        const float v = acc[i][j][e];
                        if constexpr (EPI == 0) {
                            ((u16*)Cout)[idx] = f2h(v);
                        } else {
                            ((float*)Cout)[idx] = v + ((const float*)aux)[idx];
                        }
                    }
                }
            }
        }
    }
}

// ---------- flash attention: block = (fold-qt, g, b); 4 waves = 4 heads of group g ----------
__global__ __launch_bounds__(256) void attn_kernel(const u16* __restrict__ qkv,
                                                   const u16* __restrict__ vt,
                                                   u16* __restrict__ ctxn,
                                                   const float* __restrict__ hnw) {
    __shared__ __align__(16) u16 Ks[2][2048];
    __shared__ __align__(16) u16 Vs[2][2048];
    const int bx = blockIdx.x, g = blockIdx.y, b = blockIdx.z;
    const int tid = threadIdx.x;
    const int w = tid >> 6, l = tid & 63;
    const int lr = l & 15, lg = l >> 4;
    const int h = g * 4 + w;
    const int sig = 8 * (lr >> 2) + (lr & 3);
    const int LASTROW = TPB - 1;
    const u16* vtb = vt + (size_t)(b * 4 + g) * 64 * VTS;
    const u16* kbase = qkv + (size_t)b * TPB * 1536 + 1024 + g * 64;

    const int krow = tid >> 3;
    const int ksrc = (tid & 7) ^ ((krow & 3) | (((krow >> 3) & 1) << 2));
    const int vdv = tid >> 2;
    const int vsrc = (tid & 3) ^ ((vdv >> 1) & 3);
    const int wb8 = (tid & ~63) * 8;

    const int swzr = (sig & 3) | (((sig >> 3) & 1) << 2);
    const int ka0  = sig * 64 + ((lg ^ swzr) << 3);
    const int ka0b = sig * 64 + (((lg + 4) ^ swzr) << 3);
    const int ka1  = (sig + 4) * 64 + ((lg ^ swzr) << 3);
    const int ka1b = (sig + 4) * 64 + (((lg + 4) ^ swzr) << 3);
    int kv_off[4];
    #pragma unroll
    for (int dt = 0; dt < 4; dt++) {
        const int dv = dt * 16 + lr;
        kv_off[dt] = dv * 32 + ((lg ^ ((dv >> 1) & 3)) << 3);
    }

    const float hw0 = hnw[h * 64 + 0 * 16 + lr];
    const float hw1 = hnw[h * 64 + 1 * 16 + lr];
    const float hw2 = hnw[h * 64 + 2 * 16 + lr];
    const float hw3 = hnw[h * 64 + 3 * 16 + lr];

    for (int half = 0; half < 2; half++) {
        const int qt = half ? (127 - bx) : bx;
        const int orow0 = qt * 16;
        const int qpos0 = 16 + orow0;
        const int qpos = qpos0 + lr;
        const u16* qbase = qkv + (size_t)(b * TPB + qpos) * 1536 + h * 64;
        const f16x8 qf0 = *(const f16x8*)(qbase + lg * 8);
        const f16x8 qf1 = *(const f16x8*)(qbase + 32 + lg * 8);

        float m = -INFINITY, lsum = 0.f;
        f32x4 oc[4] = {};
        const int NT = ((qpos0 + 15) >> 5) + 1;

        __syncthreads();
        gl_lds16(kbase + (size_t)krow * 1536 + ksrc * 8, Ks[0] + wb8);
        gl_lds16(vtb + (size_t)vdv * VTS + vsrc * 8, Vs[0] + wb8);

        for (int kt = 0; kt < NT; kt++) {
            const int p = kt & 1;
            const int kb = kt * 32;
            __syncthreads();
            if (kt + 1 < NT) {
                const int kb2 = kb + 32;
                int kr = kb2 + krow; if (kr > LASTROW) kr = LASTROW;
                gl_lds16(kbase + (size_t)kr * 1536 + ksrc * 8, Ks[p ^ 1] + wb8);
                gl_lds16(vtb + (size_t)vdv * VTS + kb2 + vsrc * 8, Vs[p ^ 1] + wb8);
            }
            const f16x8 a0  = *(const f16x8*)&Ks[p][ka0];
            const f16x8 a0b = *(const f16x8*)&Ks[p][ka0b];
            const f16x8 a1  = *(const f16x8*)&Ks[p][ka1];
            const f16x8 a1b = *(const f16x8*)&Ks[p][ka1b];
            f16x8 vf[4];
            #pragma unroll
            for (int dt = 0; dt < 4; dt++) vf[dt] = *(const f16x8*)&Vs[p][kv_off[dt]];

            f32x4 st0 = {}, st1 = {};
            st0 = __builtin_amdgcn_mfma_f32_16x16x32_f16(a0,  qf0, st0, 0, 0, 0);
            st0 = __builtin_amdgcn_mfma_f32_16x16x32_f16(a0b, qf1, st0, 0, 0, 0);
            st1 = __builtin_amdgcn_mfma_f32_16x16x32_f16(a1,  qf0, st1, 0, 0, 0);
            st1 = __builtin_amdgcn_mfma_f32_16x16x32_f16(a1b, qf1, st1, 0, 0, 0);

            float sv[8]; float bm = -INFINITY;
            if (kb + 31 <= qpos0) {
                #pragma unroll
                for (int j = 0; j < 4; j++) {
                    sv[j] = st0[j] * 0.125f;
                    sv[4 + j] = st1[j] * 0.125f;
                    bm = fmaxf(bm, fmaxf(sv[j], sv[4 + j]));
                }
            } else {
                #pragma unroll
                for (int j = 0; j < 4; j++) {
                    const int kva = kb + 8 * lg + j;
                    float s0 = st0[j] * 0.125f; if (kva > qpos) s0 = -INFINITY;
                    float s1 = st1[j] * 0.125f; if (kva + 4 > qpos) s1 = -INFINITY;
                    sv[j] = s0; sv[4 + j] = s1;
                    bm = fmaxf(bm, fmaxf(s0, s1));
                }
            }
            bm = fmaxf(bm, __shfl_xor(bm, 16, 64));
            bm = fmaxf(bm, __shfl_xor(bm, 32, 64));
            if (!__all(bm - m <= 8.f)) {
                const float nm = fmaxf(m, bm);
                const float sc = __expf(m - nm);
                m = nm;
                lsum *= sc;
                float scj[4];
                #pragma unroll
                for (int j = 0; j < 4; j++) scj[j] = __shfl(sc, 4 * lg + j, 64);
                #pragma unroll
                for (int dt = 0; dt < 4; dt++)
                    #pragma unroll
                    for (int j = 0; j < 4; j++) oc[dt][j] *= scj[j];
            }
            float ps = 0.f;
            f16x8 pa;
            #pragma unroll
            for (int j = 0; j < 8; j++) {
                float p2 = __expf(sv[j] - m);
                ps += p2;
                pa[j] = (_Float16)p2;
            }
            ps += __shfl_xor(ps, 16, 64); ps += __shfl_xor(ps, 32, 64);
            lsum += ps;
            #pragma unroll
            for (int dt = 0; dt < 4; dt++)
                oc[dt] = __builtin_amdgcn_mfma_f32_16x16x32_f16(pa, vf[dt], oc[dt], 0, 0, 0);
        }
        float lj[4];
        #pragma unroll
        for (int j = 0; j < 4; j++) lj[j] = __shfl(lsum, 4 * lg + j, 64);
        float o[4][4]; float ssq[4] = {0, 0, 0, 0};
        #pragma unroll
        for (int dt = 0; dt < 4; dt++)
            #pragma unroll
            for (int j = 0; j < 4; j++) {
                float v = oc[dt][j] / lj[j];
                o[dt][j] = v; ssq[j] += v * v;
            }
        float rj[4];
        #pragma unroll
        for (int j = 0; j < 4; j++) {
            float s = ssq[j];
            s += __shfl_xor(s, 1, 64); s += __shfl_xor(s, 2, 64);
            s += __shfl_xor(s, 4, 64); s += __shfl_xor(s, 8, 64);
            rj[j] = rsqrtf(s * (1.f / 64.f) + 1e-6f);
        }
        const float hwv[4] = {hw0, hw1, hw2, hw3};
        #pragma unroll
        for (int dt = 0; dt < 4; dt++) {
            #pragma unroll
            for (int j = 0; j < 4; j++) {
                const int orow = orow0 + 4 * lg + j;
                ctxn[(size_t)(b * 2048 + orow) * 1024 + h * 64 + dt * 16 + lr] =
                    f2h(o[dt][j] * rj[j] * hwv[dt]);
            }
        }
    }
}

extern "C" void kernel_launch(void* const* d_in, const int* in_sizes, int n_in,
                              void* d_out, int out_size, void* d_ws, size_t ws_size,
                              hipStream_t stream) {
    const float* x   = (const float*)d_in[0];
    const float* wn  = (const float*)d_in[1];
    const float* gw  = (const float*)d_in[2];
    const float* Wq  = (const float*)d_in[3];
    const float* Wk  = (const float*)d_in[4];
    const float* Wv  = (const float*)d_in[5];
    const float* Wo  = (const float*)d_in[6];
    const float* hnw = (const float*)d_in[7];
    const float* wf  = (const float*)d_in[8];
    const float* W1  = (const float*)d_in[9];
    const float* W3  = (const float*)d_in[10];
    const float* W2  = (const float*)d_in[11];

    char* ws = (char*)d_ws;
    u16*  wqkv = (u16*)(ws + 0);           // [1536][1024] fp16
    u16*  wo_t = (u16*)(ws + 3145728);     // [1024][1024]
    u16*  w13t = (u16*)(ws + 5242880);     // [8192][1024] packed W1|W3
    u16*  w2t  = (u16*)(ws + 22020096);    // [1024][4096]
    u16*  hbuf = (u16*)(ws + 30408704);    // [4128][1024] fp16
    u16*  qkvb = (u16*)(ws + 38862848);    // [4128][1536] fp16
    u16*  ctxn = hbuf;                     // [4096][1024] overlays hbuf (dead after QKV)
    float* scr = (float*)(ws + 30408704);  // [4096][1024] f32 split-K partial
                                           // (overlays hbuf+qkvb, dead by W2 time)
    float* yb  = (float*)(ws + 51544064);  // [4096][1024] f32
    u16*  zb   = (u16*)(ws + 68321280);    // [4096][1024] fp16
    u16*  g1   = (u16*)(ws + 76709888);    // [4096][4096] fp16 (u buffer)
    u16*  vt   = (u16*)(ws + 110264320);   // [8][64][2080] fp16 -> end 112,394,240
    float* outp = (float*)d_out;

    const dim3 blk(256);
    wconv_t_kernel<<<dim3(32, 32), blk, 0, stream>>>(Wq, wqkv, 1024, 1024);
    wconv_t_kernel<<<dim3(8, 32), blk, 0, stream>>>(Wk, wqkv + 1024 * 1024, 1024, 256);
    wconv_t_kernel<<<dim3(8, 32), blk, 0, stream>>>(Wv, wqkv + 1280 * 1024, 1024, 256);
    wconv_t_kernel<<<dim3(32, 32), blk, 0, stream>>>(Wo, wo_t, 1024, 1024);
    wconv_pack13_kernel<<<dim3(128, 32), blk, 0, stream>>>(W1, W3, w13t);
    wconv_t_kernel<<<dim3(32, 128), blk, 0, stream>>>(W2, w2t, 4096, 1024);

    rms_in_kernel<<<dim3(NROW), blk, 0, stream>>>(x, wn, gw, hbuf);
    gemm_bt<0><<<dim3(12, 33), blk, 0, stream>>>(hbuf, wqkv, qkvb, nullptr, NROW, 1536, 1024, 0, 1024, nullptr);
    vtrans_kernel<<<dim3(65, 2, 8), blk, 0, stream>>>(qkvb, vt);
    attn_kernel<<<dim3(64, 4, 2), blk, 0, stream>>>(qkvb, vt, ctxn, hnw);
    gemm_bt<1><<<dim3(8, 32), blk, 0, stream>>>(ctxn, wo_t, yb, x, 4096, 1024, 1024, 0, 1024, nullptr);
    rms_row_kernel<<<dim3(4096), blk, 0, stream>>>(yb, wf, zb);
    gemm_bt<3><<<dim3(64, 32), blk, 0, stream>>>(zb, w13t, g1, nullptr, 4096, 8192, 1024, 2, 1024, nullptr);
    gemm_bt<4><<<dim3(8, 32, 2), blk, 0, stream>>>(g1, w2t, outp, yb, 4096, 1024, 4096, 0, 2048, scr);
    combine_kernel<<<dim3(4096), blk, 0, stream>>>(outp, scr);
}

// Round 19
// 315.452 us; speedup vs baseline: 1.5594x; 1.0210x over previous
//
#include <hip/hip_runtime.h>

typedef unsigned short u16;
typedef __attribute__((ext_vector_type(8))) _Float16 f16x8;
typedef __attribute__((ext_vector_type(4))) float f32x4;

// GW=16 gw tokens; per-batch seq t = 2048+16 = 2064; total rows 2*2064 = 4128.
#define TPB 2064
#define NROW 4128
#define VTS 2080   // vt padded t-stride (zero tail)

__device__ __forceinline__ u16 f2h(float f) {
    _Float16 h = (_Float16)f;
    return __builtin_bit_cast(u16, h);
}
__device__ __forceinline__ float h2f(u16 u) {
    return (float)__builtin_bit_cast(_Float16, u);
}
__device__ __forceinline__ float wave_sum(float v) {
    #pragma unroll
    for (int m = 32; m; m >>= 1) v += __shfl_xor(v, m, 64);
    return v;
}
__device__ __forceinline__ void gl_lds16(const u16* g, u16* l) {
    __builtin_amdgcn_global_load_lds((const __attribute__((address_space(1))) void*)g,
                                     (__attribute__((address_space(3))) void*)l, 16, 0, 0);
}

// ---------- merged weight transpose-convert for the four K=1024 weights ----------
// z: 0=Wq(N=1024,dst wqkv), 1=Wk(N=256,dst wqkv+1024*1024), 2=Wv(N=256,dst wqkv+1280*1024),
//    3=Wo(N=1024,dst wo_t). Grid x=32 (n-tiles), y=32 (k-tiles); early-out when n0>=N.
__global__ __launch_bounds__(256) void wconv4_kernel(const float* __restrict__ Wq,
                                                     const float* __restrict__ Wk,
                                                     const float* __restrict__ Wv,
                                                     const float* __restrict__ Wo,
                                                     u16* __restrict__ wqkv,
                                                     u16* __restrict__ wo_t) {
    const int z = blockIdx.z;
    const int N = (z == 1 || z == 2) ? 256 : 1024;
    const int n0 = blockIdx.x * 32;
    if (n0 >= N) return;
    const float* src = (z == 0) ? Wq : (z == 1) ? Wk : (z == 2) ? Wv : Wo;
    u16* dst = (z == 0) ? wqkv : (z == 1) ? (wqkv + 1024 * 1024)
             : (z == 2) ? (wqkv + 1280 * 1024) : wo_t;
    __shared__ float tile[32][33];
    const int k0 = blockIdx.y * 32;
    const int tx = threadIdx.x & 31, ty0 = threadIdx.x >> 5;
    #pragma unroll
    for (int r = 0; r < 4; r++) {
        int ky = ty0 + r * 8;
        tile[ky][tx] = src[(size_t)(k0 + ky) * N + n0 + tx];
    }
    __syncthreads();
    #pragma unroll
    for (int r = 0; r < 4; r++) {
        int ny = ty0 + r * 8;
        dst[(size_t)(n0 + ny) * 1024 + k0 + tx] = f2h(tile[tx][ny]);
    }
}

// ---------- weight transpose-convert: f32 [K][N] -> fp16 [N][K] (W2) ----------
__global__ __launch_bounds__(256) void wconv_t_kernel(const float* __restrict__ src,
                                                      u16* __restrict__ dst, int K, int N) {
    __shared__ float tile[32][33];
    const int k0 = blockIdx.y * 32, n0 = blockIdx.x * 32;
    const int tx = threadIdx.x & 31, ty0 = threadIdx.x >> 5;
    #pragma unroll
    for (int r = 0; r < 4; r++) {
        int ky = ty0 + r * 8;
        tile[ky][tx] = src[(size_t)(k0 + ky) * N + n0 + tx];
    }
    __syncthreads();
    #pragma unroll
    for (int r = 0; r < 4; r++) {
        int ny = ty0 + r * 8;
        dst[(size_t)(n0 + ny) * K + k0 + tx] = f2h(tile[tx][ny]);
    }
}

// ---------- packed W1|W3 convert: f32 [1024][4096] x2 -> fp16 w13t [8192][1024] ----------
__global__ __launch_bounds__(256) void wconv_pack13_kernel(const float* __restrict__ W1,
                                                           const float* __restrict__ W3,
                                                           u16* __restrict__ dst) {
    __shared__ float t1[32][33];
    __shared__ float t3[32][33];
    const int f0 = blockIdx.x * 32, k0 = blockIdx.y * 32;
    const int tx = threadIdx.x & 31, ty0 = threadIdx.x >> 5;
    #pragma unroll
    for (int r = 0; r < 4; r++) {
        int ky = ty0 + r * 8;
        t1[ky][tx] = W1[(size_t)(k0 + ky) * 4096 + f0 + tx];
        t3[ky][tx] = W3[(size_t)(k0 + ky) * 4096 + f0 + tx];
    }
    __syncthreads();
    #pragma unroll
    for (int r = 0; r < 4; r++) {
        int fy = ty0 + r * 8;
        int f = f0 + fy;
        int p1 = (f >> 4) * 32 + (f & 15);
        dst[(size_t)p1 * 1024 + k0 + tx] = f2h(t1[tx][fy]);
        dst[(size_t)(p1 + 16) * 1024 + k0 + tx] = f2h(t3[tx][fy]);
    }
}

// ---------- V transpose: qkv V-cols -> vt[b*4+g][dv=64][VTS] fp16 (zero tail) ----------
__global__ __launch_bounds__(256) void vtrans_kernel(const u16* __restrict__ qkv,
                                                     u16* __restrict__ vt) {
    __shared__ u16 tile[32][33];
    const int bg = blockIdx.z;                 // b*4+g
    const int b = bg >> 2, g = bg & 3;
    const int t0 = blockIdx.x * 32, d0 = blockIdx.y * 32;
    const int tx = threadIdx.x & 31, ty0 = threadIdx.x >> 5;
    #pragma unroll
    for (int r = 0; r < 4; r++) {
        int t = t0 + ty0 + r * 8;
        u16 v = 0;
        if (t < TPB) v = qkv[(size_t)(b * TPB + t) * 1536 + 1280 + g * 64 + d0 + tx];
        tile[ty0 + r * 8][tx] = v;
    }
    __syncthreads();
    #pragma unroll
    for (int r = 0; r < 4; r++) {
        int d = d0 + ty0 + r * 8;
        vt[((size_t)bg * 64 + d) * VTS + t0 + tx] = tile[tx][ty0 + r * 8];
    }
}

// ---------- RMSNorm(x) + prepend RAW gw tokens (16) -> h fp16 [4128][1024] ----------
__global__ __launch_bounds__(256) void rms_in_kernel(const float* __restrict__ x,
                                                     const float* __restrict__ w,
                                                     const float* __restrict__ gwp,
                                                     u16* __restrict__ h) {
    const int r = blockIdx.x;                 // 0..4127
    const int b = r / TPB, pos = r - b * TPB;
    const int tid = threadIdx.x;
    u16* hr = h + (size_t)r * 1024;
    if (pos < 16) {                           // raw gw tokens (not normalized)
        const float* s = gwp + (size_t)pos * 1024;
        for (int c = tid; c < 1024; c += 256) hr[c] = f2h(s[c]);
        return;
    }
    const float* xr = x + ((size_t)b * 2048 + (pos - 16)) * 1024;
    float v[4]; float ss = 0.f;
    #pragma unroll
    for (int i = 0; i < 4; i++) { v[i] = xr[tid + 256 * i]; ss += v[i] * v[i]; }
    ss = wave_sum(ss);
    __shared__ float red[4];
    if ((tid & 63) == 0) red[tid >> 6] = ss;
    __syncthreads();
    float tot = red[0] + red[1] + red[2] + red[3];
    float rn = rsqrtf(tot * (1.f / 1024.f) + 1e-6f);
    #pragma unroll
    for (int i = 0; i < 4; i++) hr[tid + 256 * i] = f2h(v[i] * rn * w[tid + 256 * i]);
}

// ---------- RMSNorm(y f32 [4096][1024]) -> z fp16 ----------
__global__ __launch_bounds__(256) void rms_row_kernel(const float* __restrict__ in,
                                                      const float* __restrict__ w,
                                                      u16* __restrict__ out) {
    const int r = blockIdx.x;
    const int tid = threadIdx.x;
    const float* xr = in + (size_t)r * 1024;
    float v[4]; float ss = 0.f;
    #pragma unroll
    for (int i = 0; i < 4; i++) { v[i] = xr[tid + 256 * i]; ss += v[i] * v[i]; }
    ss = wave_sum(ss);
    __shared__ float red[4];
    if ((tid & 63) == 0) red[tid >> 6] = ss;
    __syncthreads();
    float tot = red[0] + red[1] + red[2] + red[3];
    float rn = rsqrtf(tot * (1.f / 1024.f) + 1e-6f);
    u16* orow = out + (size_t)r * 1024;
    #pragma unroll
    for (int i = 0; i < 4; i++) orow[tid + 256 * i] = f2h(v[i] * rn * w[tid + 256 * i]);
}

// ---------- combine: out[i] += part[i]  (f32x4 vectorized, deterministic) ----------
__global__ __launch_bounds__(256) void combine_kernel(float* __restrict__ out,
                                                      const float* __restrict__ part) {
    const size_t i = ((size_t)blockIdx.x * 256 + threadIdx.x) * 4;
    f32x4 a = *(const f32x4*)&out[i];
    const f32x4 b = *(const f32x4*)&part[i];
    a[0] += b[0]; a[1] += b[1]; a[2] += b[2]; a[3] += b[3];
    *(f32x4*)&out[i] = a;
}

// ---------- GEMM C = A * Bt^T (fp16, m97 structure) + XCD-aware block swizzle ----------
// EPI 0: fp16 C. EPI 1: f32 out = C + aux(f32). EPI 3: packed W1|W3 -> fp16 silu(c1)*c3,
//   output [M][N/2]. EPI 4: split-K over blockIdx.z: z=0 raw f32 C -> Cout2;
//   z=1 f32 C + aux -> Cout. KL = K-length per z (k0base = z*KL); K = row stride.
// swzmode: 0 = row-chunk, 1 = col-chunk, 2 = col-chunk + 8-row supertiles.
__device__ __forceinline__ void stage_tile(const u16* __restrict__ A, const u16* __restrict__ B,
                                           u16* As, u16* Bs, int m0, int n0, int k0,
                                           int M, int K, int tid) {
    const int wb = tid & ~63;
    #pragma unroll
    for (int t = 0; t < 2; t++) {
        int seg = t * 256 + tid;
        int row = seg >> 2, kc = seg & 3;
        int ar = m0 + row; if (ar > M - 1) ar = M - 1;
        gl_lds16(A + (size_t)ar * K + k0 + kc * 8, As + (size_t)(t * 256 + wb) * 8);
        gl_lds16(B + (size_t)(n0 + row) * K + k0 + kc * 8, Bs + (size_t)(t * 256 + wb) * 8);
    }
}

template <int EPI>
__global__ __launch_bounds__(256, 2) void gemm_bt(const u16* __restrict__ A,
                                                  const u16* __restrict__ B,
                                                  void* Cout,
                                                  const void* aux,
                                                  int M, int N, int K, int swzmode,
                                                  int KL, void* Cout2) {
    __shared__ __align__(16) u16 As[2][4096];
    __shared__ __align__(16) u16 Bs[2][4096];
    const int tid = threadIdx.x;
    const int gx = gridDim.x, gy = gridDim.y;
    int bxs, bys;
    if (swzmode == 2) {
        const int bid = blockIdx.y * gx + blockIdx.x;
        const int xc = bid & 7, cid = bid >> 3;
        const int cx = gx >> 3;
        const int stb = cid / (cx << 3);
        const int rem = cid - stb * (cx << 3);
        const int sm = rem / cx, sn = rem - sm * cx;
        bys = stb * 8 + sm;
        bxs = xc * cx + sn;
    } else {
        const int nwg = gx * gy;
        int lid = swzmode ? (blockIdx.x * gy + blockIdx.y) : (blockIdx.y * gx + blockIdx.x);
        const int q = nwg >> 3, rr = nwg & 7;
        const int xc = lid & 7, o = lid >> 3;
        lid = (xc < rr ? xc * (q + 1) : rr * (q + 1) + (xc - rr) * q) + o;
        if (swzmode) { bxs = lid / gy; bys = lid - bxs * gy; }
        else         { bys = lid / gx; bxs = lid - bys * gx; }
    }
    const int m0 = bys * 128, n0 = bxs * 128;
    const int kbase = blockIdx.z * KL;

    const int w = tid >> 6, l = tid & 63;
    const int wr = w >> 1, wc = w & 1, lr = l & 15, lg = l >> 4;
    f32x4 acc[4][4] = {};
    const int NT = KL >> 5;
    stage_tile(A, B, As[0], Bs[0], m0, n0, kbase, M, K, tid);
    for (int t = 0; t < NT; t++) {
        const int p = t & 1;
        __syncthreads();                       // drains vmcnt(0): staged tile ready
        if (t + 1 < NT) stage_tile(A, B, As[p ^ 1], Bs[p ^ 1], m0, n0, kbase + (t + 1) * 32, M, K, tid);
        f16x8 af[4], bf[4];
        #pragma unroll
        for (int i = 0; i < 4; i++) {
            af[i] = *(const f16x8*)&As[p][(wr * 64 + i * 16 + lr) * 32 + lg * 8];
            bf[i] = *(const f16x8*)&Bs[p][(wc * 64 + i * 16 + lr) * 32 + lg * 8];
        }
        #pragma unroll
        for (int i = 0; i < 4; i++)
            #pragma unroll
            for (int j = 0; j < 4; j++)
                acc[i][j] = __builtin_amdgcn_mfma_f32_16x16x32_f16(af[i], bf[j], acc[i][j], 0, 0, 0);
    }
    if constexpr (EPI == 3) {
        // fused SwiGLU epilogue: j pairs (0,1)=(W1,W3) cols ucol0, (2,3) -> ucol0+16
        const int ldc = N >> 1;
        const int ucol0 = ((n0 + wc * 64) >> 1) + lr;
        #pragma unroll
        for (int i = 0; i < 4; i++) {
            const int rowb = m0 + wr * 64 + i * 16 + lg * 4;
            #pragma unroll
            for (int e = 0; e < 4; e++) {
                const int r2 = rowb + e;
                const float a0 = acc[i][0][e], a1 = acc[i][1][e];
                const float b0 = acc[i][2][e], b1 = acc[i][3][e];
                ((u16*)Cout)[(size_t)r2 * ldc + ucol0] = f2h(a0 / (1.f + __expf(-a0)) * a1);
                ((u16*)Cout)[(size_t)r2 * ldc + ucol0 + 16] = f2h(b0 / (1.f + __expf(-b0)) * b1);
            }
        }
    } else if constexpr (EPI == 4) {
        float* dst0 = (float*)Cout2;
        float* dst1 = (float*)Cout;
        const bool z0 = (blockIdx.z == 0);
        #pragma unroll
        for (int i = 0; i < 4; i++) {
            const int rowb = m0 + wr * 64 + i * 16 + lg * 4;
            #pragma unroll
            for (int j = 0; j < 4; j++) {
                const int col = n0 + wc * 64 + j * 16 + lr;
                #pragma unroll
                for (int e = 0; e < 4; e++) {
                    const int r2 = rowb + e;
                    const size_t idx = (size_t)r2 * N + col;
                    const float v = acc[i][j][e];
                    if (z0) dst0[idx] = v;
                    else    dst1[idx] = v + ((const float*)aux)[idx];
                }
            }
        }
    } else {
        #pragma unroll
        for (int i = 0; i < 4; i++) {
            const int rowb = m0 + wr * 64 + i * 16 + lg * 4;
            #pragma unroll
            for (int j = 0; j < 4; j++) {
                const int col = n0 + wc * 64 + j * 16 + lr;
                #pragma unroll
                for (int e = 0; e < 4; e++) {
                    const int r2 = rowb + e;
                    if (r2 < M) {
                        const size_t idx = (size_t)r2 * N + col;
                        const float v = acc[i][j][e];
                        if constexpr (EPI == 0) {
                            ((u16*)Cout)[idx] = f2h(v);
                        } else {
                            ((float*)Cout)[idx] = v + ((const float*)aux)[idx];
                        }
                    }
                }
            }
        }
    }
}

// ---------- flash attention: block = (fold-qt, g, b); 4 waves = 4 heads of group g ----------
__global__ __launch_bounds__(256) void attn_kernel(const u16* __restrict__ qkv,
                                                   const u16* __restrict__ vt,
                                                   u16* __restrict__ ctxn,
                                                   const float* __restrict__ hnw) {
    __shared__ __align__(16) u16 Ks[2][2048];
    __shared__ __align__(16) u16 Vs[2][2048];
    const int bx = blockIdx.x, g = blockIdx.y, b = blockIdx.z;
    const int tid = threadIdx.x;
    const int w = tid >> 6, l = tid & 63;
    const int lr = l & 15, lg = l >> 4;
    const int h = g * 4 + w;
    const int sig = 8 * (lr >> 2) + (lr & 3);
    const int LASTROW = TPB - 1;
    const u16* vtb = vt + (size_t)(b * 4 + g) * 64 * VTS;
    const u16* kbase = qkv + (size_t)b * TPB * 1536 + 1024 + g * 64;

    const int krow = tid >> 3;
    const int ksrc = (tid & 7) ^ ((krow & 3) | (((krow >> 3) & 1) << 2));
    const int vdv = tid >> 2;
    const int vsrc = (tid & 3) ^ ((vdv >> 1) & 3);
    const int wb8 = (tid & ~63) * 8;

    const int swzr = (sig & 3) | (((sig >> 3) & 1) << 2);
    const int ka0  = sig * 64 + ((lg ^ swzr) << 3);
    const int ka0b = sig * 64 + (((lg + 4) ^ swzr) << 3);
    const int ka1  = (sig + 4) * 64 + ((lg ^ swzr) << 3);
    const int ka1b = (sig + 4) * 64 + (((lg + 4) ^ swzr) << 3);
    int kv_off[4];
    #pragma unroll
    for (int dt = 0; dt < 4; dt++) {
        const int dv = dt * 16 + lr;
        kv_off[dt] = dv * 32 + ((lg ^ ((dv >> 1) & 3)) << 3);
    }

    const float hw0 = hnw[h * 64 + 0 * 16 + lr];
    const float hw1 = hnw[h * 64 + 1 * 16 + lr];
    const float hw2 = hnw[h * 64 + 2 * 16 + lr];
    const float hw3 = hnw[h * 64 + 3 * 16 + lr];

    for (int half = 0; half < 2; half++) {
        const int qt = half ? (127 - bx) : bx;
        const int orow0 = qt * 16;
        const int qpos0 = 16 + orow0;
        const int qpos = qpos0 + lr;
        const u16* qbase = qkv + (size_t)(b * TPB + qpos) * 1536 + h * 64;
        const f16x8 qf0 = *(const f16x8*)(qbase + lg * 8);
        const f16x8 qf1 = *(const f16x8*)(qbase + 32 + lg * 8);

        float m = -INFINITY, lsum = 0.f;
        f32x4 oc[4] = {};
        const int NT = ((qpos0 + 15) >> 5) + 1;

        __syncthreads();
        gl_lds16(kbase + (size_t)krow * 1536 + ksrc * 8, Ks[0] + wb8);
        gl_lds16(vtb + (size_t)vdv * VTS + vsrc * 8, Vs[0] + wb8);

        for (int kt = 0; kt < NT; kt++) {
            const int p = kt & 1;
            const int kb = kt * 32;
            __syncthreads();
            if (kt + 1 < NT) {
                const int kb2 = kb + 32;
                int kr = kb2 + krow; if (kr > LASTROW) kr = LASTROW;
                gl_lds16(kbase + (size_t)kr * 1536 + ksrc * 8, Ks[p ^ 1] + wb8);
                gl_lds16(vtb + (size_t)vdv * VTS + kb2 + vsrc * 8, Vs[p ^ 1] + wb8);
            }
            const f16x8 a0  = *(const f16x8*)&Ks[p][ka0];
            const f16x8 a0b = *(const f16x8*)&Ks[p][ka0b];
            const f16x8 a1  = *(const f16x8*)&Ks[p][ka1];
            const f16x8 a1b = *(const f16x8*)&Ks[p][ka1b];
            f16x8 vf[4];
            #pragma unroll
            for (int dt = 0; dt < 4; dt++) vf[dt] = *(const f16x8*)&Vs[p][kv_off[dt]];

            f32x4 st0 = {}, st1 = {};
            st0 = __builtin_amdgcn_mfma_f32_16x16x32_f16(a0,  qf0, st0, 0, 0, 0);
            st0 = __builtin_amdgcn_mfma_f32_16x16x32_f16(a0b, qf1, st0, 0, 0, 0);
            st1 = __builtin_amdgcn_mfma_f32_16x16x32_f16(a1,  qf0, st1, 0, 0, 0);
            st1 = __builtin_amdgcn_mfma_f32_16x16x32_f16(a1b, qf1, st1, 0, 0, 0);

            float sv[8]; float bm = -INFINITY;
            if (kb + 31 <= qpos0) {
                #pragma unroll
                for (int j = 0; j < 4; j++) {
                    sv[j] = st0[j] * 0.125f;
                    sv[4 + j] = st1[j] * 0.125f;
                    bm = fmaxf(bm, fmaxf(sv[j], sv[4 + j]));
                }
            } else {
                #pragma unroll
                for (int j = 0; j < 4; j++) {
                    const int kva = kb + 8 * lg + j;
                    float s0 = st0[j] * 0.125f; if (kva > qpos) s0 = -INFINITY;
                    float s1 = st1[j] * 0.125f; if (kva + 4 > qpos) s1 = -INFINITY;
                    sv[j] = s0; sv[4 + j] = s1;
                    bm = fmaxf(bm, fmaxf(s0, s1));
                }
            }
            bm = fmaxf(bm, __shfl_xor(bm, 16, 64));
            bm = fmaxf(bm, __shfl_xor(bm, 32, 64));
            if (!__all(bm - m <= 8.f)) {
                const float nm = fmaxf(m, bm);
                const float sc = __expf(m - nm);
                m = nm;
                lsum *= sc;
                float scj[4];
                #pragma unroll
                for (int j = 0; j < 4; j++) scj[j] = __shfl(sc, 4 * lg + j, 64);
                #pragma unroll
                for (int dt = 0; dt < 4; dt++)
                    #pragma unroll
                    for (int j = 0; j < 4; j++) oc[dt][j] *= scj[j];
            }
            float ps = 0.f;
            f16x8 pa;
            #pragma unroll
            for (int j = 0; j < 8; j++) {
                float p2 = __expf(sv[j] - m);
                ps += p2;
                pa[j] = (_Float16)p2;
            }
            ps += __shfl_xor(ps, 16, 64); ps += __shfl_xor(ps, 32, 64);
            lsum += ps;
            #pragma unroll
            for (int dt = 0; dt < 4; dt++)
                oc[dt] = __builtin_amdgcn_mfma_f32_16x16x32_f16(pa, vf[dt], oc[dt], 0, 0, 0);
        }
        float lj[4];
        #pragma unroll
        for (int j = 0; j < 4; j++) lj[j] = __shfl(lsum, 4 * lg + j, 64);
        float o[4][4]; float ssq[4] = {0, 0, 0, 0};
        #pragma unroll
        for (int dt = 0; dt < 4; dt++)
            #pragma unroll
            for (int j = 0; j < 4; j++) {
                float v = oc[dt][j] / lj[j];
                o[dt][j] = v; ssq[j] += v * v;
            }
        float rj[4];
        #pragma unroll
        for (int j = 0; j < 4; j++) {
            float s = ssq[j];
            s += __shfl_xor(s, 1, 64); s += __shfl_xor(s, 2, 64);
            s += __shfl_xor(s, 4, 64); s += __shfl_xor(s, 8, 64);
            rj[j] = rsqrtf(s * (1.f / 64.f) + 1e-6f);
        }
        const float hwv[4] = {hw0, hw1, hw2, hw3};
        #pragma unroll
        for (int dt = 0; dt < 4; dt++) {
            #pragma unroll
            for (int j = 0; j < 4; j++) {
                const int orow = orow0 + 4 * lg + j;
                ctxn[(size_t)(b * 2048 + orow) * 1024 + h * 64 + dt * 16 + lr] =
                    f2h(o[dt][j] * rj[j] * hwv[dt]);
            }
        }
    }
}

extern "C" void kernel_launch(void* const* d_in, const int* in_sizes, int n_in,
                              void* d_out, int out_size, void* d_ws, size_t ws_size,
                              hipStream_t stream) {
    const float* x   = (const float*)d_in[0];
    const float* wn  = (const float*)d_in[1];
    const float* gw  = (const float*)d_in[2];
    const float* Wq  = (const float*)d_in[3];
    const float* Wk  = (const float*)d_in[4];
    const float* Wv  = (const float*)d_in[5];
    const float* Wo  = (const float*)d_in[6];
    const float* hnw = (const float*)d_in[7];
    const float* wf  = (const float*)d_in[8];
    const float* W1  = (const float*)d_in[9];
    const float* W3  = (const float*)d_in[10];
    const float* W2  = (const float*)d_in[11];

    char* ws = (char*)d_ws;
    u16*  wqkv = (u16*)(ws + 0);           // [1536][1024] fp16
    u16*  wo_t = (u16*)(ws + 3145728);     // [1024][1024]
    u16*  w13t = (u16*)(ws + 5242880);     // [8192][1024] packed W1|W3
    u16*  w2t  = (u16*)(ws + 22020096);    // [1024][4096]
    u16*  hbuf = (u16*)(ws + 30408704);    // [4128][1024] fp16
    u16*  qkvb = (u16*)(ws + 38862848);    // [4128][1536] fp16
    u16*  ctxn = hbuf;                     // [4096][1024] overlays hbuf (dead after QKV)
    float* scr = (float*)(ws + 30408704);  // [4096][1024] f32 split-K partial
    float* yb  = (float*)(ws + 51544064);  // [4096][1024] f32
    u16*  zb   = (u16*)(ws + 68321280);    // [4096][1024] fp16
    u16*  g1   = (u16*)(ws + 76709888);    // [4096][4096] fp16 (u buffer)
    u16*  vt   = (u16*)(ws + 110264320);   // [8][64][2080] fp16 -> end 112,394,240
    float* outp = (float*)d_out;

    const dim3 blk(256);
    wconv4_kernel<<<dim3(32, 32, 4), blk, 0, stream>>>(Wq, Wk, Wv, Wo, wqkv, wo_t);
    wconv_pack13_kernel<<<dim3(128, 32), blk, 0, stream>>>(W1, W3, w13t);
    wconv_t_kernel<<<dim3(32, 128), blk, 0, stream>>>(W2, w2t, 4096, 1024);

    rms_in_kernel<<<dim3(NROW), blk, 0, stream>>>(x, wn, gw, hbuf);
    gemm_bt<0><<<dim3(12, 33), blk, 0, stream>>>(hbuf, wqkv, qkvb, nullptr, NROW, 1536, 1024, 0, 1024, nullptr);
    vtrans_kernel<<<dim3(65, 2, 8), blk, 0, stream>>>(qkvb, vt);
    attn_kernel<<<dim3(64, 4, 2), blk, 0, stream>>>(qkvb, vt, ctxn, hnw);
    gemm_bt<1><<<dim3(8, 32), blk, 0, stream>>>(ctxn, wo_t, yb, x, 4096, 1024, 1024, 0, 1024, nullptr);
    rms_row_kernel<<<dim3(4096), blk, 0, stream>>>(yb, wf, zb);
    gemm_bt<3><<<dim3(64, 32), blk, 0, stream>>>(zb, w13t, g1, nullptr, 4096, 8192, 1024, 2, 1024, nullptr);
    gemm_bt<4><<<dim3(8, 32, 2), blk, 0, stream>>>(g1, w2t, outp, yb, 4096, 1024, 4096, 0, 2048, scr);
    combine_kernel<<<dim3(4096), blk, 0, stream>>>(outp, scr);
}

// Round 20
// 309.369 us; speedup vs baseline: 1.5900x; 1.0197x over previous
//
#include <hip/hip_runtime.h>

typedef unsigned short u16;
typedef __attribute__((ext_vector_type(8))) _Float16 f16x8;
typedef __attribute__((ext_vector_type(4))) float f32x4;

// GW=16 gw tokens; per-batch seq t = 2048+16 = 2064; total rows 2*2064 = 4128.
#define TPB 2064
#define NROW 4128
#define VTS 2112   // vt padded t-stride (zero tail; covers kb..kb+127 reads)

__device__ __forceinline__ u16 f2h(float f) {
    _Float16 h = (_Float16)f;
    return __builtin_bit_cast(u16, h);
}
__device__ __forceinline__ float h2f(u16 u) {
    return (float)__builtin_bit_cast(_Float16, u);
}
__device__ __forceinline__ float wave_sum(float v) {
    #pragma unroll
    for (int m = 32; m; m >>= 1) v += __shfl_xor(v, m, 64);
    return v;
}
__device__ __forceinline__ void gl_lds16(const u16* g, u16* l) {
    __builtin_amdgcn_global_load_lds((const __attribute__((address_space(1))) void*)g,
                                     (__attribute__((address_space(3))) void*)l, 16, 0, 0);
}

// ---------- merged weight transpose-convert for the four K=1024 weights ----------
__global__ __launch_bounds__(256) void wconv4_kernel(const float* __restrict__ Wq,
                                                     const float* __restrict__ Wk,
                                                     const float* __restrict__ Wv,
                                                     const float* __restrict__ Wo,
                                                     u16* __restrict__ wqkv,
                                                     u16* __restrict__ wo_t) {
    const int z = blockIdx.z;
    const int N = (z == 1 || z == 2) ? 256 : 1024;
    const int n0 = blockIdx.x * 32;
    if (n0 >= N) return;
    const float* src = (z == 0) ? Wq : (z == 1) ? Wk : (z == 2) ? Wv : Wo;
    u16* dst = (z == 0) ? wqkv : (z == 1) ? (wqkv + 1024 * 1024)
             : (z == 2) ? (wqkv + 1280 * 1024) : wo_t;
    __shared__ float tile[32][33];
    const int k0 = blockIdx.y * 32;
    const int tx = threadIdx.x & 31, ty0 = threadIdx.x >> 5;
    #pragma unroll
    for (int r = 0; r < 4; r++) {
        int ky = ty0 + r * 8;
        tile[ky][tx] = src[(size_t)(k0 + ky) * N + n0 + tx];
    }
    __syncthreads();
    #pragma unroll
    for (int r = 0; r < 4; r++) {
        int ny = ty0 + r * 8;
        dst[(size_t)(n0 + ny) * 1024 + k0 + tx] = f2h(tile[tx][ny]);
    }
}

// ---------- weight transpose-convert: f32 [K][N] -> fp16 [N][K] (W2) ----------
__global__ __launch_bounds__(256) void wconv_t_kernel(const float* __restrict__ src,
                                                      u16* __restrict__ dst, int K, int N) {
    __shared__ float tile[32][33];
    const int k0 = blockIdx.y * 32, n0 = blockIdx.x * 32;
    const int tx = threadIdx.x & 31, ty0 = threadIdx.x >> 5;
    #pragma unroll
    for (int r = 0; r < 4; r++) {
        int ky = ty0 + r * 8;
        tile[ky][tx] = src[(size_t)(k0 + ky) * N + n0 + tx];
    }
    __syncthreads();
    #pragma unroll
    for (int r = 0; r < 4; r++) {
        int ny = ty0 + r * 8;
        dst[(size_t)(n0 + ny) * K + k0 + tx] = f2h(tile[tx][ny]);
    }
}

// ---------- packed W1|W3 convert: f32 [1024][4096] x2 -> fp16 w13t [8192][1024] ----------
__global__ __launch_bounds__(256) void wconv_pack13_kernel(const float* __restrict__ W1,
                                                           const float* __restrict__ W3,
                                                           u16* __restrict__ dst) {
    __shared__ float t1[32][33];
    __shared__ float t3[32][33];
    const int f0 = blockIdx.x * 32, k0 = blockIdx.y * 32;
    const int tx = threadIdx.x & 31, ty0 = threadIdx.x >> 5;
    #pragma unroll
    for (int r = 0; r < 4; r++) {
        int ky = ty0 + r * 8;
        t1[ky][tx] = W1[(size_t)(k0 + ky) * 4096 + f0 + tx];
        t3[ky][tx] = W3[(size_t)(k0 + ky) * 4096 + f0 + tx];
    }
    __syncthreads();
    #pragma unroll
    for (int r = 0; r < 4; r++) {
        int fy = ty0 + r * 8;
        int f = f0 + fy;
        int p1 = (f >> 4) * 32 + (f & 15);
        dst[(size_t)p1 * 1024 + k0 + tx] = f2h(t1[tx][fy]);
        dst[(size_t)(p1 + 16) * 1024 + k0 + tx] = f2h(t3[tx][fy]);
    }
}

// ---------- V transpose: qkv V-cols -> vt[b*4+g][dv=64][VTS] fp16 (zero tail) ----------
__global__ __launch_bounds__(256) void vtrans_kernel(const u16* __restrict__ qkv,
                                                     u16* __restrict__ vt) {
    __shared__ u16 tile[32][33];
    const int bg = blockIdx.z;                 // b*4+g
    const int b = bg >> 2, g = bg & 3;
    const int t0 = blockIdx.x * 32, d0 = blockIdx.y * 32;
    const int tx = threadIdx.x & 31, ty0 = threadIdx.x >> 5;
    #pragma unroll
    for (int r = 0; r < 4; r++) {
        int t = t0 + ty0 + r * 8;
        u16 v = 0;
        if (t < TPB) v = qkv[(size_t)(b * TPB + t) * 1536 + 1280 + g * 64 + d0 + tx];
        tile[ty0 + r * 8][tx] = v;
    }
    __syncthreads();
    #pragma unroll
    for (int r = 0; r < 4; r++) {
        int d = d0 + ty0 + r * 8;
        vt[((size_t)bg * 64 + d) * VTS + t0 + tx] = tile[tx][ty0 + r * 8];
    }
}

// ---------- RMSNorm(x) + prepend RAW gw tokens (16) -> h fp16 [4128][1024] ----------
__global__ __launch_bounds__(256) void rms_in_kernel(const float* __restrict__ x,
                                                     const float* __restrict__ w,
                                                     const float* __restrict__ gwp,
                                                     u16* __restrict__ h) {
    const int r = blockIdx.x;                 // 0..4127
    const int b = r / TPB, pos = r - b * TPB;
    const int tid = threadIdx.x;
    u16* hr = h + (size_t)r * 1024;
    if (pos < 16) {                           // raw gw tokens (not normalized)
        const float* s = gwp + (size_t)pos * 1024;
        for (int c = tid; c < 1024; c += 256) hr[c] = f2h(s[c]);
        return;
    }
    const float* xr = x + ((size_t)b * 2048 + (pos - 16)) * 1024;
    float v[4]; float ss = 0.f;
    #pragma unroll
    for (int i = 0; i < 4; i++) { v[i] = xr[tid + 256 * i]; ss += v[i] * v[i]; }
    ss = wave_sum(ss);
    __shared__ float red[4];
    if ((tid & 63) == 0) red[tid >> 6] = ss;
    __syncthreads();
    float tot = red[0] + red[1] + red[2] + red[3];
    float rn = rsqrtf(tot * (1.f / 1024.f) + 1e-6f);
    #pragma unroll
    for (int i = 0; i < 4; i++) hr[tid + 256 * i] = f2h(v[i] * rn * w[tid + 256 * i]);
}

// ---------- RMSNorm(y f32 [4096][1024]) -> z fp16 ----------
__global__ __launch_bounds__(256) void rms_row_kernel(const float* __restrict__ in,
                                                      const float* __restrict__ w,
                                                      u16* __restrict__ out) {
    const int r = blockIdx.x;
    const int tid = threadIdx.x;
    const float* xr = in + (size_t)r * 1024;
    float v[4]; float ss = 0.f;
    #pragma unroll
    for (int i = 0; i < 4; i++) { v[i] = xr[tid + 256 * i]; ss += v[i] * v[i]; }
    ss = wave_sum(ss);
    __shared__ float red[4];
    if ((tid & 63) == 0) red[tid >> 6] = ss;
    __syncthreads();
    float tot = red[0] + red[1] + red[2] + red[3];
    float rn = rsqrtf(tot * (1.f / 1024.f) + 1e-6f);
    u16* orow = out + (size_t)r * 1024;
    #pragma unroll
    for (int i = 0; i < 4; i++) orow[tid + 256 * i] = f2h(v[i] * rn * w[tid + 256 * i]);
}

// ---------- combine: out[i] += part[i]  (f32x4 vectorized, deterministic) ----------
__global__ __launch_bounds__(256) void combine_kernel(float* __restrict__ out,
                                                      const float* __restrict__ part) {
    const size_t i = ((size_t)blockIdx.x * 256 + threadIdx.x) * 4;
    f32x4 a = *(const f32x4*)&out[i];
    const f32x4 b = *(const f32x4*)&part[i];
    a[0] += b[0]; a[1] += b[1]; a[2] += b[2]; a[3] += b[3];
    *(f32x4*)&out[i] = a;
}

// ---------- GEMM C = A * Bt^T (fp16, m97 structure) + XCD swizzle + T2 LDS swizzle ----
// LDS[row][c] holds global chunk c ^ ((row>>1)&3) (16B chunks, pre-swizzled source,
// linear LDS dest per rule #21); reads use chunk lg ^ ((row>>1)&3) -> 2-way banks.
__device__ __forceinline__ void stage_tile(const u16* __restrict__ A, const u16* __restrict__ B,
                                           u16* As, u16* Bs, int m0, int n0, int k0,
                                           int M, int K, int tid) {
    const int wb = tid & ~63;
    #pragma unroll
    for (int t = 0; t < 2; t++) {
        int seg = t * 256 + tid;
        int row = seg >> 2, kc = seg & 3;
        int kcs = (kc ^ ((row >> 1) & 3)) * 8;
        int ar = m0 + row; if (ar > M - 1) ar = M - 1;
        gl_lds16(A + (size_t)ar * K + k0 + kcs, As + (size_t)(t * 256 + wb) * 8);
        gl_lds16(B + (size_t)(n0 + row) * K + k0 + kcs, Bs + (size_t)(t * 256 + wb) * 8);
    }
}

template <int EPI>
__global__ __launch_bounds__(256, 2) void gemm_bt(const u16* __restrict__ A,
                                                  const u16* __restrict__ B,
                                                  void* Cout,
                                                  const void* aux,
                                                  int M, int N, int K, int swzmode,
                                                  int KL, void* Cout2) {
    __shared__ __align__(16) u16 As[2][4096];
    __shared__ __align__(16) u16 Bs[2][4096];
    const int tid = threadIdx.x;
    const int gx = gridDim.x, gy = gridDim.y;
    int bxs, bys;
    if (swzmode == 2) {
        const int bid = blockIdx.y * gx + blockIdx.x;
        const int xc = bid & 7, cid = bid >> 3;
        const int cx = gx >> 3;
        const int stb = cid / (cx << 3);
        const int rem = cid - stb * (cx << 3);
        const int sm = rem / cx, sn = rem - sm * cx;
        bys = stb * 8 + sm;
        bxs = xc * cx + sn;
    } else {
        const int nwg = gx * gy;
        int lid = swzmode ? (blockIdx.x * gy + blockIdx.y) : (blockIdx.y * gx + blockIdx.x);
        const int q = nwg >> 3, rr = nwg & 7;
        const int xc = lid & 7, o = lid >> 3;
        lid = (xc < rr ? xc * (q + 1) : rr * (q + 1) + (xc - rr) * q) + o;
        if (swzmode) { bxs = lid / gy; bys = lid - bxs * gy; }
        else         { bys = lid / gx; bxs = lid - bys * gx; }
    }
    const int m0 = bys * 128, n0 = bxs * 128;
    const int kbase = blockIdx.z * KL;

    const int w = tid >> 6, l = tid & 63;
    const int wr = w >> 1, wc = w & 1, lr = l & 15, lg = l >> 4;
    // precompute swizzled fragment offsets (u16 units)
    int aoff[4], boff[4];
    #pragma unroll
    for (int i = 0; i < 4; i++) {
        const int ra = wr * 64 + i * 16 + lr;
        aoff[i] = ra * 32 + ((lg ^ ((ra >> 1) & 3)) << 3);
        const int rb = wc * 64 + i * 16 + lr;
        boff[i] = rb * 32 + ((lg ^ ((rb >> 1) & 3)) << 3);
    }
    f32x4 acc[4][4] = {};
    const int NT = KL >> 5;
    stage_tile(A, B, As[0], Bs[0], m0, n0, kbase, M, K, tid);
    for (int t = 0; t < NT; t++) {
        const int p = t & 1;
        __syncthreads();                       // drains vmcnt(0): staged tile ready
        if (t + 1 < NT) stage_tile(A, B, As[p ^ 1], Bs[p ^ 1], m0, n0, kbase + (t + 1) * 32, M, K, tid);
        f16x8 af[4], bf[4];
        #pragma unroll
        for (int i = 0; i < 4; i++) {
            af[i] = *(const f16x8*)&As[p][aoff[i]];
            bf[i] = *(const f16x8*)&Bs[p][boff[i]];
        }
        #pragma unroll
        for (int i = 0; i < 4; i++)
            #pragma unroll
            for (int j = 0; j < 4; j++)
                acc[i][j] = __builtin_amdgcn_mfma_f32_16x16x32_f16(af[i], bf[j], acc[i][j], 0, 0, 0);
    }
    if constexpr (EPI == 3) {
        // fused SwiGLU epilogue: j pairs (0,1)=(W1,W3) cols ucol0, (2,3) -> ucol0+16
        const int ldc = N >> 1;
        const int ucol0 = ((n0 + wc * 64) >> 1) + lr;
        #pragma unroll
        for (int i = 0; i < 4; i++) {
            const int rowb = m0 + wr * 64 + i * 16 + lg * 4;
            #pragma unroll
            for (int e = 0; e < 4; e++) {
                const int r2 = rowb + e;
                const float a0 = acc[i][0][e], a1 = acc[i][1][e];
                const float b0 = acc[i][2][e], b1 = acc[i][3][e];
                ((u16*)Cout)[(size_t)r2 * ldc + ucol0] = f2h(a0 / (1.f + __expf(-a0)) * a1);
                ((u16*)Cout)[(size_t)r2 * ldc + ucol0 + 16] = f2h(b0 / (1.f + __expf(-b0)) * b1);
            }
        }
    } else if constexpr (EPI == 4) {
        float* dst0 = (float*)Cout2;
        float* dst1 = (float*)Cout;
        const bool z0 = (blockIdx.z == 0);
        #pragma unroll
        for (int i = 0; i < 4; i++) {
            const int rowb = m0 + wr * 64 + i * 16 + lg * 4;
            #pragma unroll
            for (int j = 0; j < 4; j++) {
                const int col = n0 + wc * 64 + j * 16 + lr;
                #pragma unroll
                for (int e = 0; e < 4; e++) {
                    const int r2 = rowb + e;
                    const size_t idx = (size_t)r2 * N + col;
                    const float v = acc[i][j][e];
                    if (z0) dst0[idx] = v;
                    else    dst1[idx] = v + ((const float*)aux)[idx];
                }
            }
        }
    } else {
        #pragma unroll
        for (int i = 0; i < 4; i++) {
            const int rowb = m0 + wr * 64 + i * 16 + lg * 4;
            #pragma unroll
            for (int j = 0; j < 4; j++) {
                const int col = n0 + wc * 64 + j * 16 + lr;
                #pragma unroll
                for (int e = 0; e < 4; e++) {
                    const int r2 = rowb + e;
                    if (r2 < M) {
                        const size_t idx = (size_t)r2 * N + col;
                        const float v = acc[i][j][e];
                        if constexpr (EPI == 0) {
                            ((u16*)Cout)[idx] = f2h(v);
                        } else {
                            ((float*)Cout)[idx] = v + ((const float*)aux)[idx];
                        }
                    }
                }
            }
        }
    }
}

// ---------- flash attention: KVBLK=64 staged per barrier, two 32-row sub-steps ----------
// block = (fold-qt, g, b); 4 waves = 4 heads of group g. K tile [64][64] swizzled with
// chunk ^= (row + 2*(row>>3))&7; V^T tile [64 dv][64 t] with chunk ^= dv&7.
__global__ __launch_bounds__(256) void attn_kernel(const u16* __restrict__ qkv,
                                                   const u16* __restrict__ vt,
                                                   u16* __restrict__ ctxn,
                                                   const float* __restrict__ hnw) {
    __shared__ __align__(16) u16 Ks[2][4096];
    __shared__ __align__(16) u16 Vs[2][4096];
    const int bx = blockIdx.x, g = blockIdx.y, b = blockIdx.z;
    const int tid = threadIdx.x;
    const int w = tid >> 6, l = tid & 63;
    const int lr = l & 15, lg = l >> 4;
    const int h = g * 4 + w;
    const int sig = 8 * (lr >> 2) + (lr & 3);
    const int LASTROW = TPB - 1;
    const u16* vtb = vt + (size_t)(b * 4 + g) * 64 * VTS;
    const u16* kbase = qkv + (size_t)b * TPB * 1536 + 1024 + g * 64;

    // staging constants: 2 K-loads + 2 V-loads per thread per 64-row tile
    const int wb8 = (tid & ~63) * 8;
    int srow[2], ksrc[2], vsrc[2];
    #pragma unroll
    for (int s = 0; s < 2; s++) {
        const int slot = s * 256 + tid;
        const int row = slot >> 3, kc = slot & 7;
        srow[s] = row;
        ksrc[s] = (kc ^ ((row + 2 * (row >> 3)) & 7)) * 8;
        vsrc[s] = (kc ^ (row & 7)) * 8;
    }

    // read-side swizzled offsets (u16 units; rows have 64 u16 = 8 chunks of 8)
    int ka0[2], ka0b[2], ka1[2], ka1b[2], kvo[2][4];
    #pragma unroll
    for (int sub = 0; sub < 2; sub++) {
        const int r0 = sub * 32 + sig, r1 = r0 + 4;
        const int s0 = (r0 + 2 * (r0 >> 3)) & 7, s1 = (r1 + 2 * (r1 >> 3)) & 7;
        ka0[sub]  = r0 * 64 + ((lg ^ s0) << 3);
        ka0b[sub] = r0 * 64 + (((lg + 4) ^ s0) << 3);
        ka1[sub]  = r1 * 64 + ((lg ^ s1) << 3);
        ka1b[sub] = r1 * 64 + (((lg + 4) ^ s1) << 3);
        #pragma unroll
        for (int dt = 0; dt < 4; dt++) {
            const int dv = dt * 16 + lr;
            kvo[sub][dt] = dv * 64 + (((lg + sub * 4) ^ (dv & 7)) << 3);
        }
    }

    const float hw0 = hnw[h * 64 + 0 * 16 + lr];
    const float hw1 = hnw[h * 64 + 1 * 16 + lr];
    const float hw2 = hnw[h * 64 + 2 * 16 + lr];
    const float hw3 = hnw[h * 64 + 3 * 16 + lr];

    for (int half = 0; half < 2; half++) {
        const int qt = half ? (127 - bx) : bx;
        const int orow0 = qt * 16;
        const int qpos0 = 16 + orow0;
        const int qpos = qpos0 + lr;
        const u16* qbase = qkv + (size_t)(b * TPB + qpos) * 1536 + h * 64;
        const f16x8 qf0 = *(const f16x8*)(qbase + lg * 8);
        const f16x8 qf1 = *(const f16x8*)(qbase + 32 + lg * 8);

        float m = -INFINITY, lsum = 0.f;
        f32x4 oc[4] = {};
        const int NT = ((qpos0 + 15) >> 6) + 1;   // 64-row tiles

        __syncthreads();                           // protect LDS reuse across halves
        #pragma unroll
        for (int s = 0; s < 2; s++) {
            int kr = srow[s]; if (kr > LASTROW) kr = LASTROW;
            gl_lds16(kbase + (size_t)kr * 1536 + ksrc[s], Ks[0] + s * 2048 + wb8);
            gl_lds16(vtb + (size_t)srow[s] * VTS + vsrc[s], Vs[0] + s * 2048 + wb8);
        }

        for (int kt = 0; kt < NT; kt++) {
            const int p = kt & 1;
            const int kb = kt * 64;
            __syncthreads();                       // tile kb staged
            if (kt + 1 < NT) {
                const int kb2 = kb + 64;
                #pragma unroll
                for (int s = 0; s < 2; s++) {
                    int kr = kb2 + srow[s]; if (kr > LASTROW) kr = LASTROW;
                    gl_lds16(kbase + (size_t)kr * 1536 + ksrc[s], Ks[p ^ 1] + s * 2048 + wb8);
                    gl_lds16(vtb + (size_t)srow[s] * VTS + kb2 + vsrc[s], Vs[p ^ 1] + s * 2048 + wb8);
                }
            }
            #pragma unroll
            for (int sub = 0; sub < 2; sub++) {
                const int kb32 = kb + sub * 32;
                if (kb32 <= qpos0 + 15) {
                    const f16x8 a0  = *(const f16x8*)&Ks[p][ka0[sub]];
                    const f16x8 a0b = *(const f16x8*)&Ks[p][ka0b[sub]];
                    const f16x8 a1  = *(const f16x8*)&Ks[p][ka1[sub]];
                    const f16x8 a1b = *(const f16x8*)&Ks[p][ka1b[sub]];
                    f16x8 vf[4];
                    #pragma unroll
                    for (int dt = 0; dt < 4; dt++) vf[dt] = *(const f16x8*)&Vs[p][kvo[sub][dt]];

                    f32x4 st0 = {}, st1 = {};
                    st0 = __builtin_amdgcn_mfma_f32_16x16x32_f16(a0,  qf0, st0, 0, 0, 0);
                    st0 = __builtin_amdgcn_mfma_f32_16x16x32_f16(a0b, qf1, st0, 0, 0, 0);
                    st1 = __builtin_amdgcn_mfma_f32_16x16x32_f16(a1,  qf0, st1, 0, 0, 0);
                    st1 = __builtin_amdgcn_mfma_f32_16x16x32_f16(a1b, qf1, st1, 0, 0, 0);

                    float sv[8]; float bm = -INFINITY;
                    if (kb32 + 31 <= qpos0) {
                        #pragma unroll
                        for (int j = 0; j < 4; j++) {
                            sv[j] = st0[j] * 0.125f;
                            sv[4 + j] = st1[j] * 0.125f;
                            bm = fmaxf(bm, fmaxf(sv[j], sv[4 + j]));
                        }
                    } else {
                        #pragma unroll
                        for (int j = 0; j < 4; j++) {
                            const int kva = kb32 + 8 * lg + j;
                            float s0 = st0[j] * 0.125f; if (kva > qpos) s0 = -INFINITY;
                            float s1 = st1[j] * 0.125f; if (kva + 4 > qpos) s1 = -INFINITY;
                            sv[j] = s0; sv[4 + j] = s1;
                            bm = fmaxf(bm, fmaxf(s0, s1));
                        }
                    }
                    bm = fmaxf(bm, __shfl_xor(bm, 16, 64));
                    bm = fmaxf(bm, __shfl_xor(bm, 32, 64));
                    if (!__all(bm - m <= 8.f)) {
                        const float nm = fmaxf(m, bm);
                        const float sc = __expf(m - nm);
                        m = nm;
                        lsum *= sc;
                        float scj[4];
                        #pragma unroll
                        for (int j = 0; j < 4; j++) scj[j] = __shfl(sc, 4 * lg + j, 64);
                        #pragma unroll
                        for (int dt = 0; dt < 4; dt++)
                            #pragma unroll
                            for (int j = 0; j < 4; j++) oc[dt][j] *= scj[j];
                    }
                    float ps = 0.f;
                    f16x8 pa;
                    #pragma unroll
                    for (int j = 0; j < 8; j++) {
                        float p2 = __expf(sv[j] - m);
                        ps += p2;
                        pa[j] = (_Float16)p2;
                    }
                    ps += __shfl_xor(ps, 16, 64); ps += __shfl_xor(ps, 32, 64);
                    lsum += ps;
                    #pragma unroll
                    for (int dt = 0; dt < 4; dt++)
                        oc[dt] = __builtin_amdgcn_mfma_f32_16x16x32_f16(pa, vf[dt], oc[dt], 0, 0, 0);
                }
            }
        }
        float lj[4];
        #pragma unroll
        for (int j = 0; j < 4; j++) lj[j] = __shfl(lsum, 4 * lg + j, 64);
        float o[4][4]; float ssq[4] = {0, 0, 0, 0};
        #pragma unroll
        for (int dt = 0; dt < 4; dt++)
            #pragma unroll
            for (int j = 0; j < 4; j++) {
                float v = oc[dt][j] / lj[j];
                o[dt][j] = v; ssq[j] += v * v;
            }
        float rj[4];
        #pragma unroll
        for (int j = 0; j < 4; j++) {
            float s = ssq[j];
            s += __shfl_xor(s, 1, 64); s += __shfl_xor(s, 2, 64);
            s += __shfl_xor(s, 4, 64); s += __shfl_xor(s, 8, 64);
            rj[j] = rsqrtf(s * (1.f / 64.f) + 1e-6f);
        }
        const float hwv[4] = {hw0, hw1, hw2, hw3};
        #pragma unroll
        for (int dt = 0; dt < 4; dt++) {
            #pragma unroll
            for (int j = 0; j < 4; j++) {
                const int orow = orow0 + 4 * lg + j;
                ctxn[(size_t)(b * 2048 + orow) * 1024 + h * 64 + dt * 16 + lr] =
                    f2h(o[dt][j] * rj[j] * hwv[dt]);
            }
        }
    }
}

extern "C" void kernel_launch(void* const* d_in, const int* in_sizes, int n_in,
                              void* d_out, int out_size, void* d_ws, size_t ws_size,
                              hipStream_t stream) {
    const float* x   = (const float*)d_in[0];
    const float* wn  = (const float*)d_in[1];
    const float* gw  = (const float*)d_in[2];
    const float* Wq  = (const float*)d_in[3];
    const float* Wk  = (const float*)d_in[4];
    const float* Wv  = (const float*)d_in[5];
    const float* Wo  = (const float*)d_in[6];
    const float* hnw = (const float*)d_in[7];
    const float* wf  = (const float*)d_in[8];
    const float* W1  = (const float*)d_in[9];
    const float* W3  = (const float*)d_in[10];
    const float* W2  = (const float*)d_in[11];

    char* ws = (char*)d_ws;
    u16*  wqkv = (u16*)(ws + 0);           // [1536][1024] fp16
    u16*  wo_t = (u16*)(ws + 3145728);     // [1024][1024]
    u16*  w13t = (u16*)(ws + 5242880);     // [8192][1024] packed W1|W3
    u16*  w2t  = (u16*)(ws + 22020096);    // [1024][4096]
    u16*  hbuf = (u16*)(ws + 30408704);    // [4128][1024] fp16
    u16*  qkvb = (u16*)(ws + 38862848);    // [4128][1536] fp16
    u16*  ctxn = hbuf;                     // [4096][1024] overlays hbuf (dead after QKV)
    float* scr = (float*)(ws + 30408704);  // [4096][1024] f32 split-K partial
    float* yb  = (float*)(ws + 51544064);  // [4096][1024] f32
    u16*  zb   = (u16*)(ws + 68321280);    // [4096][1024] fp16
    u16*  g1   = (u16*)(ws + 76709888);    // [4096][4096] fp16 (u buffer)
    u16*  vt   = (u16*)(ws + 110264320);   // [8][64][2112] fp16 -> end 112,427,008
    float* outp = (float*)d_out;

    const dim3 blk(256);
    wconv4_kernel<<<dim3(32, 32, 4), blk, 0, stream>>>(Wq, Wk, Wv, Wo, wqkv, wo_t);
    wconv_pack13_kernel<<<dim3(128, 32), blk, 0, stream>>>(W1, W3, w13t);
    wconv_t_kernel<<<dim3(32, 128), blk, 0, stream>>>(W2, w2t, 4096, 1024);

    rms_in_kernel<<<dim3(NROW), blk, 0, stream>>>(x, wn, gw, hbuf);
    gemm_bt<0><<<dim3(12, 33), blk, 0, stream>>>(hbuf, wqkv, qkvb, nullptr, NROW, 1536, 1024, 0, 1024, nullptr);
    vtrans_kernel<<<dim3(66, 2, 8), blk, 0, stream>>>(qkvb, vt);
    attn_kernel<<<dim3(64, 4, 2), blk, 0, stream>>>(qkvb, vt, ctxn, hnw);
    gemm_bt<1><<<dim3(8, 32), blk, 0, stream>>>(ctxn, wo_t, yb, x, 4096, 1024, 1024, 0, 1024, nullptr);
    rms_row_kernel<<<dim3(4096), blk, 0, stream>>>(yb, wf, zb);
    gemm_bt<3><<<dim3(64, 32), blk, 0, stream>>>(zb, w13t, g1, nullptr, 4096, 8192, 1024, 2, 1024, nullptr);
    gemm_bt<4><<<dim3(8, 32, 2), blk, 0, stream>>>(g1, w2t, outp, yb, 4096, 1024, 4096, 0, 2048, scr);
    combine_kernel<<<dim3(4096), blk, 0, stream>>>(outp, scr);
}